// Round 10
// baseline (934.534 us; speedup 1.0000x reference)
//
#include <hip/hip_runtime.h>
#include <math.h>

// Problem constants
#define NN 20000
#define NE 320000
#define FD 128
#define RBFN 20
#define RC_ 5.0f
#define NITER 3
#define NMOL 64
#define F3 384
#define F2 256
#define PI_ 3.14159265358979323846f
#define KB 128
#define LPAD 8
#define SDS 392   // u16 stride per sdrep edge row (384 + 8 pad)
#define BM2 32    // node-path rows/block (more blocks/CU — validated lever, r9)

typedef __attribute__((ext_vector_type(8))) short  bf16x8;
typedef __attribute__((ext_vector_type(4))) float  floatx4;
typedef unsigned short u16;
typedef unsigned int   u32;

__device__ __forceinline__ u16 f2b(float x) {
    union { float f; unsigned int u; } v; v.f = x;
    unsigned int u = v.u;
    return (u16)((u + 0x7fffu + ((u >> 16) & 1u)) >> 16);   // RNE
}
__device__ __forceinline__ float b2f(u16 x) {
    union { unsigned int u; float f; } v; v.u = ((unsigned int)x) << 16;
    return v.f;
}
__device__ __forceinline__ float blo(u32 w) {
    union { unsigned int u; float f; } v; v.u = w << 16; return v.f;
}
__device__ __forceinline__ float bhi(u32 w) {
    union { unsigned int u; float f; } v; v.u = w & 0xffff0000u; return v.f;
}
__device__ __forceinline__ u32 pack2(float a, float b) {
    return (u32)f2b(a) | ((u32)f2b(b) << 16);
}

// ---------------------------------------------------------------- fused one-time init
__global__ __launch_bounds__(256) void init_all_kernel(
    const float* s0, int n0, const float* s1, int n1, const float* s2, int n2,
    const float* s3, int n3, const float* s4, int n4, const float* s5, int n5,
    const float* s6, int n6, u16* __restrict__ wdst,
    const float* __restrict__ ew, u16* __restrict__ ewb,
    const int* __restrict__ z, const float* __restrict__ emb,
    float* __restrict__ s, u16* __restrict__ sbf,
    float* __restrict__ v_a, int* __restrict__ v_pk_i, int* __restrict__ cnt,
    float* __restrict__ out)
{
    int idx = blockIdx.x * 256 + threadIdx.x;
    if (idx < NN * F3) v_a[idx] = 0.f;
    if (idx < NN * F3 / 2) v_pk_i[idx] = 0;
    if (idx < NN) cnt[idx] = 0;
    if (idx < NMOL) out[idx] = 0.f;
    if (idx < NN * FD) {
        int n = idx >> 7, f = idx & 127;
        float v = emb[z[n] * FD + f];
        s[idx] = v; sbf[idx] = f2b(v);
    }
    if (idx < NITER * F3 * 32) {
        int k = idx & 31;
        int row = idx >> 5;
        ewb[idx] = (k < RBFN) ? f2b(ew[row * RBFN + k]) : (u16)0;
    }
    {
        int w = idx;
        u16* dst = wdst;
        if (w < n0) { dst[w] = f2b(s0[w]); return; } w -= n0; dst += n0;
        if (w < n1) { dst[w] = f2b(s1[w]); return; } w -= n1; dst += n1;
        if (w < n2) { dst[w] = f2b(s2[w]); return; } w -= n2; dst += n2;
        if (w < n3) { dst[w] = f2b(s3[w]); return; } w -= n3; dst += n3;
        if (w < n4) { dst[w] = f2b(s4[w]); return; } w -= n4; dst += n4;
        if (w < n5) { dst[w] = f2b(s5[w]); return; } w -= n5; dst += n5;
        if (w < n6) { dst[w] = f2b(s6[w]); }
    }
}

// ---------------------------------------------------------------- CSR build
__global__ __launch_bounds__(256) void csr_count_kernel(const int* __restrict__ graph,
    int* __restrict__ cnt)
{
    int e = blockIdx.x * 256 + threadIdx.x;
    if (e >= NE) return;
    atomicAdd(&cnt[graph[2 * e]], 1);
}

__global__ __launch_bounds__(1024) void csr_scan_kernel(const int* __restrict__ cnt,
    int* __restrict__ row_ptr, int* __restrict__ cursor)
{
    __shared__ int sd[1024];
    int tid = threadIdx.x;
    const int chunk = (NN + 1023) / 1024;
    int start = tid * chunk;
    int end = start + chunk; if (end > NN) end = NN;
    int sum = 0;
    for (int j = start; j < end; j++) sum += cnt[j];
    sd[tid] = sum;
    __syncthreads();
    for (int off = 1; off < 1024; off <<= 1) {
        int v = 0;
        if (tid >= off) v = sd[tid - off];
        __syncthreads();
        if (tid >= off) sd[tid] += v;
        __syncthreads();
    }
    int run = (tid == 0) ? 0 : sd[tid - 1];
    for (int j = start; j < end; j++) {
        row_ptr[j] = run;
        cursor[j]  = run;
        run += cnt[j];
    }
    if (tid == 0) row_ptr[NN] = NE;
}

__global__ __launch_bounds__(256) void csr_scatter_kernel(const int* __restrict__ graph,
    int* __restrict__ cursor, int* __restrict__ edge_list)
{
    int e = blockIdx.x * 256 + threadIdx.x;
    if (e >= NE) return;
    int p = atomicAdd(&cursor[graph[2 * e]], 1);
    edge_list[p] = e;
}

// Permuted edge streams in CSR order; Chebyshev sin recurrence; vectorized rbf stores.
__global__ __launch_bounds__(256) void edge_stream_kernel(
    const int* __restrict__ edge_list, const int* __restrict__ graph,
    const float* __restrict__ dist, const float* __restrict__ sense,
    u16* __restrict__ rbf_bf, float* __restrict__ cut_p,
    float* __restrict__ sense_p, int* __restrict__ dst_p)
{
    int j = blockIdx.x * 256 + threadIdx.x;
    if (j >= NE) return;
    int e = edge_list[j];
    float d = dist[e];
    float inv = 1.f / d;
    float base = PI_ * d / RC_;
    float s1, c1;
    __sincosf(base, &s1, &c1);
    float twoc = c1 + c1;
    u16 tmp[32];
    float sprev = 0.f, scur = s1;
    #pragma unroll
    for (int k = 0; k < RBFN; k++) {
        tmp[k] = f2b(scur * inv);
        float snext = twoc * scur - sprev;
        sprev = scur; scur = snext;
    }
    #pragma unroll
    for (int k = RBFN; k < 32; k++) tmp[k] = 0;
    u16* rb = rbf_bf + (size_t)j * 32;
    #pragma unroll
    for (int x = 0; x < 32; x += 8)
        *(bf16x8*)&rb[x] = *(const bf16x8*)&tmp[x];
    cut_p[j] = 0.5f * (c1 + 1.f) * (d < RC_ ? 1.f : 0.f);
    dst_p[j] = graph[2 * e + 1];
    sense_p[3 * j + 0] = sense[3 * e + 0];
    sense_p[3 * j + 1] = sense[3 * e + 1];
    sense_p[3 * j + 2] = sense[3 * e + 2];
}

// ---------------------------------------------------------------- iter-0 message MLP (BM=32)
// Ob = (silu(A@W1^T + b1)) @ W2^T + b2, K=128.  Structure = m2un's appended mlp1 with a
// global A-stage prologue (validated form).  PACK output layout for edge gather.
__global__ __launch_bounds__(256) void mlp1_kernel(const u16* __restrict__ A,
    const u16* __restrict__ W1, const float* __restrict__ b1,
    const u16* __restrict__ W2, const float* __restrict__ b2,
    u16* __restrict__ Ob, int M)
{
    __shared__ u16 As[BM2][KB + LPAD];
    __shared__ u16 Ws[128][KB + LPAD];
    u16 (*T)[KB + LPAD] = &Ws[64];     // alias: valid only after GEMM1 consumed Ws
    const int bm = blockIdx.x * BM2;
    const int tid = threadIdx.x;
    const int wave = tid >> 6, lane = tid & 63;
    const int wrow = (wave >> 1) * 16;
    const int wn1  = (wave & 1) * 64;
    const int wn   = (wave & 1) * 32;
    const int quad = lane >> 4, lr = lane & 15;
    const int r = tid >> 2, q = tid & 3;
    const int r3 = tid >> 3, c16 = (tid & 7) * 16;

    floatx4 acc1[4];
    #pragma unroll
    for (int j = 0; j < 4; j++) acc1[j] = (floatx4)0.f;

    {
        int gm = bm + r3;
        u16* dA = &As[r3][c16];
        if (gm < M) {
            const u16* ap = A + (size_t)gm * KB + c16;
            *(bf16x8*)&dA[0] = *(const bf16x8*)(ap);
            *(bf16x8*)&dA[8] = *(const bf16x8*)(ap + 8);
        } else {
            *(bf16x8*)&dA[0] = (bf16x8)0;
            *(bf16x8*)&dA[8] = (bf16x8)0;
        }
        #pragma unroll
        for (int h = 0; h < 2; h++) {
            int wr = r + h * 64;
            const u16* wp = W1 + (size_t)wr * KB + q * 32;
            u16* dW = &Ws[wr][q * 32];
            #pragma unroll
            for (int x = 0; x < 32; x += 8)
                *(bf16x8*)&dW[x] = *(const bf16x8*)(wp + x);
        }
    }
    __syncthreads();
    #pragma unroll
    for (int kk = 0; kk < KB; kk += 32) {
        bf16x8 a0 = *(const bf16x8*)&As[wrow + lr][kk + quad * 8];
        #pragma unroll
        for (int j = 0; j < 4; j++) {
            bf16x8 b = *(const bf16x8*)&Ws[wn1 + j * 16 + lr][kk + quad * 8];
            acc1[j] = __builtin_amdgcn_mfma_f32_16x16x32_bf16(a0, b, acc1[j], 0, 0, 0);
        }
    }
    __syncthreads();   // Ws consumed -> T region writable
    #pragma unroll
    for (int j = 0; j < 4; j++) {
        int col = wn1 + j * 16 + lr;
        float bb = b1[col];
        #pragma unroll
        for (int rr = 0; rr < 4; rr++) {
            int row = wrow + quad * 4 + rr;
            float v = acc1[j][rr] + bb;
            v = v / (1.f + __expf(-v));
            T[row][col] = f2b(v);
        }
    }
    for (int pp = 0; pp < 6; pp++) {
        const int c0 = pp * 64;
        {
            const u16* wp = W2 + (size_t)(c0 + r) * KB + q * 32;
            u16* dW = &Ws[r][q * 32];
            #pragma unroll
            for (int x = 0; x < 32; x += 8)
                *(bf16x8*)&dW[x] = *(const bf16x8*)(wp + x);
        }
        __syncthreads();   // (pp==0: also covers T-write)
        floatx4 acc2[2];
        #pragma unroll
        for (int j = 0; j < 2; j++) acc2[j] = (floatx4)0.f;
        #pragma unroll
        for (int kk = 0; kk < KB; kk += 32) {
            bf16x8 a0 = *(const bf16x8*)&T[wrow + lr][kk + quad * 8];
            bf16x8 b0 = *(const bf16x8*)&Ws[wn + lr     ][kk + quad * 8];
            bf16x8 b1 = *(const bf16x8*)&Ws[wn + 16 + lr][kk + quad * 8];
            acc2[0] = __builtin_amdgcn_mfma_f32_16x16x32_bf16(a0, b0, acc2[0], 0, 0, 0);
            acc2[1] = __builtin_amdgcn_mfma_f32_16x16x32_bf16(a0, b1, acc2[1], 0, 0, 0);
        }
        #pragma unroll
        for (int j = 0; j < 2; j++) {
            int gn = c0 + wn + j * 16 + lr;
            float bb = b2[gn];
            #pragma unroll
            for (int rr = 0; rr < 4; rr++) {
                int gm = bm + wrow + quad * 4 + rr;
                if (gm < M) {
                    u16 val = f2b(acc2[j][rr] + bb);
                    int off = (gn < 256) ? ((gn & 127) * 2 + (gn >> 7))
                                         : (256 + (gn & 127));
                    Ob[(size_t)gm * F3 + off] = val;
                }
            }
        }
        __syncthreads();
    }
}

// Dual GEMM: U = A@Wu^T, V = A@Wv^T (K=128, Nc=128). bf16 outs. BM=32 re-tile (1875 blocks).
// A staged once (r3/c16 pattern); bn (output-col half) folded in-block; each wave owns one
// 16-row tile x one 32-col half.
__global__ __launch_bounds__(256) void gemm_uv(const u16* __restrict__ A,
    const u16* __restrict__ Wu, const u16* __restrict__ Wv,
    u16* __restrict__ U, u16* __restrict__ V, int M)
{
    __shared__ u16 As[BM2][KB + LPAD];
    __shared__ u16 Bu[64][KB + LPAD];
    __shared__ u16 Bv[64][KB + LPAD];
    const int bm = blockIdx.x * BM2;
    const int tid = threadIdx.x;
    const int r = tid >> 2;
    const int q = tid & 3;
    const int r3 = tid >> 3, c16 = (tid & 7) * 16;
    const int wave = tid >> 6;
    const int lane = tid & 63;
    const int wrow = (wave >> 1) * 16;
    const int wn = (wave & 1) * 32;
    const int quad = lane >> 4;
    const int lr = lane & 15;

    {
        int gm = bm + r3;
        u16* dA = &As[r3][c16];
        if (gm < M) {
            const u16* ap = A + (size_t)gm * KB + c16;
            *(bf16x8*)&dA[0] = *(const bf16x8*)(ap);
            *(bf16x8*)&dA[8] = *(const bf16x8*)(ap + 8);
        } else {
            *(bf16x8*)&dA[0] = (bf16x8)0;
            *(bf16x8*)&dA[8] = (bf16x8)0;
        }
    }

    #pragma unroll
    for (int bn = 0; bn < FD; bn += 64) {
        {
            int gn = bn + r;
            const u16* up = Wu + (size_t)gn * KB + q * 32;
            const u16* vp = Wv + (size_t)gn * KB + q * 32;
            u16* dU = &Bu[r][q * 32];
            u16* dV = &Bv[r][q * 32];
            #pragma unroll
            for (int x = 0; x < 32; x += 8) {
                *(bf16x8*)&dU[x] = *(const bf16x8*)(up + x);
                *(bf16x8*)&dV[x] = *(const bf16x8*)(vp + x);
            }
        }
        __syncthreads();
        floatx4 au[2], av[2];
        #pragma unroll
        for (int j = 0; j < 2; j++) { au[j] = (floatx4)0.f; av[j] = (floatx4)0.f; }
        #pragma unroll
        for (int kk = 0; kk < KB; kk += 32) {
            bf16x8 a0 = *(const bf16x8*)&As[wrow + lr][kk + quad * 8];
            bf16x8 u0 = *(const bf16x8*)&Bu[wn + lr     ][kk + quad * 8];
            bf16x8 u1 = *(const bf16x8*)&Bu[wn + 16 + lr][kk + quad * 8];
            bf16x8 v0 = *(const bf16x8*)&Bv[wn + lr     ][kk + quad * 8];
            bf16x8 v1 = *(const bf16x8*)&Bv[wn + 16 + lr][kk + quad * 8];
            au[0] = __builtin_amdgcn_mfma_f32_16x16x32_bf16(a0, u0, au[0], 0, 0, 0);
            au[1] = __builtin_amdgcn_mfma_f32_16x16x32_bf16(a0, u1, au[1], 0, 0, 0);
            av[0] = __builtin_amdgcn_mfma_f32_16x16x32_bf16(a0, v0, av[0], 0, 0, 0);
            av[1] = __builtin_amdgcn_mfma_f32_16x16x32_bf16(a0, v1, av[1], 0, 0, 0);
        }
        #pragma unroll
        for (int j = 0; j < 2; j++) {
            int gn = bn + wn + j * 16 + lr;
            #pragma unroll
            for (int rr = 0; rr < 4; rr++) {
                int gm = bm + wrow + quad * 4 + rr;
                if (gm < M) {
                    U[(size_t)gm * FD + gn] = f2b(au[j][rr]);
                    V[(size_t)gm * FD + gn] = f2b(av[j][rr]);
                }
            }
        }
        __syncthreads();   // Bu/Bv fully consumed before restage
    }
}

// ---------------------------------------------------------------- edge aggregate (MFMA dist_rep)
// 256 threads/node — PROVEN 138µs form, do not modify.
__global__ __launch_bounds__(256) void edge_mfma_kernel(
    const u16* __restrict__ rbf_bf, const float* __restrict__ cut_p,
    const float* __restrict__ sense_p, const int* __restrict__ dst_p,
    const u16* __restrict__ ewb, const float* __restrict__ eb,
    const u16* __restrict__ a_pk, const float* __restrict__ s_in,
    const float* __restrict__ v_in, const u16* __restrict__ v_pk,
    const int* __restrict__ row_ptr,
    float* __restrict__ s_out, u16* __restrict__ s_obf,
    float* __restrict__ v_out, u16* __restrict__ v_obf)
{
    __shared__ u16   sdrep[16 * SDS];
    __shared__ float scut[16];
    __shared__ float ssen[16][4];
    __shared__ int   sdst[16];
    __shared__ float red[4 * 128];

    const int n = blockIdx.x;
    const int tid = threadIdx.x;
    const int wave = tid >> 6;
    const int lane = tid & 63;
    const int quad = lane >> 4;
    const int lr = lane & 15;
    const int f = tid & 127;
    const int half = tid >> 7;

    int beg = row_ptr[n], end = row_ptr[n + 1];
    float accs = 0.f, accv0 = 0.f, accv1 = 0.f, accv2 = 0.f;

    for (int t0 = beg; t0 < end; t0 += 16) {
        int cnt = end - t0; if (cnt > 16) cnt = 16;
        __syncthreads();
        if (tid < 16) {
            scut[tid] = (tid < cnt) ? cut_p[t0 + tid] : 0.f;
            sdst[tid] = (tid < cnt) ? dst_p[t0 + tid] : 0;
        }
        if (tid >= 64 && tid < 64 + 3 * cnt) {
            int x = tid - 64;
            ssen[x / 3][x % 3] = sense_p[3 * t0 + x];
        }
        bf16x8 afrag;
        int ge = t0 + lr;
        if (ge < end) afrag = *(const bf16x8*)&rbf_bf[(size_t)ge * 32 + quad * 8];
        else          afrag = (bf16x8)0;
        floatx4 dacc[6];
        #pragma unroll
        for (int nt = 0; nt < 6; nt++) {
            int nrow = (wave * 6 + nt) * 16 + lr;
            bf16x8 bfrag = *(const bf16x8*)&ewb[(size_t)nrow * 32 + quad * 8];
            dacc[nt] = __builtin_amdgcn_mfma_f32_16x16x32_bf16(afrag, bfrag, (floatx4)0.f, 0, 0, 0);
        }
        __syncthreads();
        #pragma unroll
        for (int nt = 0; nt < 6; nt++) {
            int ncol = (wave * 6 + nt) * 16 + lr;
            float ebn = eb[ncol];
            #pragma unroll
            for (int rr = 0; rr < 4; rr++) {
                int e = quad * 4 + rr;
                sdrep[e * SDS + ncol] = f2b((dacc[nt][rr] + ebn) * scut[e]);
            }
        }
        __syncthreads();
        int nh = cnt - half * 8; if (nh > 8) nh = 8;
        for (int k = 0; k < nh; k++) {
            int e = half * 8 + k;
            int dst = sdst[e];
            const u16* sr = &sdrep[e * SDS];
            float drv = b2f(sr[f]);
            float drs = b2f(sr[FD + f]);
            float drd = b2f(sr[2 * FD + f]);
            const u16* ar = a_pk + (size_t)dst * F3;
            u32 ap = *(const u32*)(ar + f * 2);
            float rv = b2f((u16)(ap & 0xffff)) * drv;
            float rs = b2f((u16)(ap >> 16))    * drs;
            float rd = b2f(ar[256 + f])        * drd;
            accs += rs;
            const u16* vr = v_pk + (size_t)dst * F3;
            u32 vp = *(const u32*)(vr + f * 2);
            accv0 += b2f((u16)(vp & 0xffff)) * rv + ssen[e][0] * rd;
            accv1 += b2f((u16)(vp >> 16))    * rv + ssen[e][1] * rd;
            accv2 += b2f(vr[256 + f])        * rv + ssen[e][2] * rd;
        }
    }
    __syncthreads();
    if (half == 1) {
        red[f] = accs; red[128 + f] = accv0; red[256 + f] = accv1; red[384 + f] = accv2;
    }
    __syncthreads();
    if (half == 0) {
        accs  += red[f];       accv0 += red[128 + f];
        accv1 += red[256 + f]; accv2 += red[384 + f];
        int nb = n * FD + f;
        float so = s_in[nb] + 2.f * accs;
        s_out[nb] = so; s_obf[nb] = f2b(so);
        int vb = n * F3 + f;
        float w0 = v_in[vb]           + 2.f * accv0;
        float w1 = v_in[vb + FD]      + 2.f * accv1;
        float w2 = v_in[vb + 2 * FD]  + 2.f * accv2;
        v_out[vb]          = w0; v_obf[vb]          = f2b(w0);
        v_out[vb + FD]     = w1; v_obf[vb + FD]     = f2b(w1);
        v_out[vb + 2 * FD] = w2; v_obf[vb + 2 * FD] = f2b(w2);
    }
}

// ---------------------------------------------------------------- fused mlp2 + build_h + update + NEXT
// BM=32 (625 blocks). T aliased onto Ws[64..127]; ass chunk does node update inline and
// deposits fresh s into As.  LAST=false appends next mlp1; LAST=true appends head with
// direct per-molecule atomicAdd into out (no mol_reduce kernel).
template<bool LAST>
__global__ __launch_bounds__(256) void mlp2_update_next_kernel(
    const u16* __restrict__ sbf_mid, const float* __restrict__ s_mid,
    const float* __restrict__ v_mid,
    const u16* __restrict__ Uv, const u16* __restrict__ Vv,
    const u16* __restrict__ W1, const float* __restrict__ b1,
    const u16* __restrict__ W2, const float* __restrict__ b2,
    float* __restrict__ s_out,
    float* __restrict__ v_out, u16* __restrict__ v_pk,
    const u16* __restrict__ N_W1, const float* __restrict__ N_b1,
    const u16* __restrict__ N_W2, const float* __restrict__ N_b2,
    u16* __restrict__ a_pk,
    const u16* __restrict__ H_W1, const float* __restrict__ H_b1,
    const float* __restrict__ ow2, const float* __restrict__ ob2,
    const int* __restrict__ gidx, float* __restrict__ outp, int M)
{
    __shared__ u16 As[BM2][KB + LPAD];
    __shared__ u16 Ws[128][KB + LPAD];
    u16 (*T)[KB + LPAD] = &Ws[64];     // alias: valid only after GEMM1 consumed Ws
    const int bm = blockIdx.x * BM2;
    const int tid = threadIdx.x;
    const int wave = tid >> 6, lane = tid & 63;
    const int wrow = (wave >> 1) * 16;      // 0 or 16
    const int wn1  = (wave & 1) * 64;       // GEMM1 col-half
    const int wn   = (wave & 1) * 32;       // GEMM2 col-half
    const int quad = lane >> 4, lr = lane & 15;
    const int r = tid >> 2, q = tid & 3;    // Ws staging (128 rows)
    const int r3 = tid >> 3, c16 = (tid & 7) * 16;  // As staging (32 rows x 128 cols)

    floatx4 acc1[4];
    #pragma unroll
    for (int j = 0; j < 4; j++) acc1[j] = (floatx4)0.f;

    // ---- GEMM1, ko chunk 0: A cols = s_mid bf16
    {
        int gm = bm + r3;
        u16* dA = &As[r3][c16];
        if (gm < M) {
            const u16* ap = sbf_mid + (size_t)gm * FD + c16;
            *(bf16x8*)&dA[0] = *(const bf16x8*)(ap);
            *(bf16x8*)&dA[8] = *(const bf16x8*)(ap + 8);
        } else {
            *(bf16x8*)&dA[0] = (bf16x8)0;
            *(bf16x8*)&dA[8] = (bf16x8)0;
        }
        #pragma unroll
        for (int h = 0; h < 2; h++) {
            int wr = r + h * 64;
            const u16* wp = W1 + (size_t)wr * F2 + q * 32;
            u16* dW = &Ws[wr][q * 32];
            #pragma unroll
            for (int x = 0; x < 32; x += 8)
                *(bf16x8*)&dW[x] = *(const bf16x8*)(wp + x);
        }
    }
    __syncthreads();
    #pragma unroll
    for (int kk = 0; kk < KB; kk += 32) {
        bf16x8 a0 = *(const bf16x8*)&As[wrow + lr][kk + quad * 8];
        #pragma unroll
        for (int j = 0; j < 4; j++) {
            bf16x8 b = *(const bf16x8*)&Ws[wn1 + j * 16 + lr][kk + quad * 8];
            acc1[j] = __builtin_amdgcn_mfma_f32_16x16x32_bf16(a0, b, acc1[j], 0, 0, 0);
        }
    }
    __syncthreads();
    // ---- GEMM1, ko chunk 1: A cols = |Vv| computed inline (build_h fused)
    {
        int gm = bm + r3;
        u16* dA = &As[r3][c16];
        if (gm < M) {
            const u16* vvp = Vv + (size_t)gm * F3 + c16;
            #pragma unroll
            for (int t = 0; t < 2; t++) {
                bf16x8 c0 = *(const bf16x8*)(vvp + t * 8);
                bf16x8 c1 = *(const bf16x8*)(vvp + FD + t * 8);
                bf16x8 c2 = *(const bf16x8*)(vvp + 2 * FD + t * 8);
                #pragma unroll
                for (int x = 0; x < 8; x++) {
                    float a = b2f((u16)c0[x]);
                    float b = b2f((u16)c1[x]);
                    float c = b2f((u16)c2[x]);
                    dA[t * 8 + x] = f2b(sqrtf(a * a + b * b + c * c));
                }
            }
        } else {
            *(bf16x8*)&dA[0] = (bf16x8)0;
            *(bf16x8*)&dA[8] = (bf16x8)0;
        }
        #pragma unroll
        for (int h = 0; h < 2; h++) {
            int wr = r + h * 64;
            const u16* wp = W1 + (size_t)wr * F2 + KB + q * 32;
            u16* dW = &Ws[wr][q * 32];
            #pragma unroll
            for (int x = 0; x < 32; x += 8)
                *(bf16x8*)&dW[x] = *(const bf16x8*)(wp + x);
        }
    }
    __syncthreads();
    #pragma unroll
    for (int kk = 0; kk < KB; kk += 32) {
        bf16x8 a0 = *(const bf16x8*)&As[wrow + lr][kk + quad * 8];
        #pragma unroll
        for (int j = 0; j < 4; j++) {
            bf16x8 b = *(const bf16x8*)&Ws[wn1 + j * 16 + lr][kk + quad * 8];
            acc1[j] = __builtin_amdgcn_mfma_f32_16x16x32_bf16(a0, b, acc1[j], 0, 0, 0);
        }
    }
    __syncthreads();   // all MFMAs done reading Ws -> T region writable
    // T = silu(acc1 + b1) as bf16  (rows 0..31 of Ws[64..])
    #pragma unroll
    for (int j = 0; j < 4; j++) {
        int col = wn1 + j * 16 + lr;
        float bb = b1[col];
        #pragma unroll
        for (int rr = 0; rr < 4; rr++) {
            int row = wrow + quad * 4 + rr;
            float v = acc1[j][rr] + bb;
            v = v / (1.f + __expf(-v));
            T[row][col] = f2b(v);
        }
    }

    // ---- GEMM2: pieces staged into Ws[0..63]; order (avv,asv,ass) per f-half.
    float avvr[2][4], asvr[2][4];
    #pragma unroll
    for (int pp = 0; pp < 6; pp++) {
        const int part  = pp / 3;
        const int piece = pp % 3;
        const int c0 = piece * 128 + part * 64;
        {
            const u16* wp = W2 + (size_t)(c0 + r) * KB + q * 32;
            u16* dW = &Ws[r][q * 32];
            #pragma unroll
            for (int x = 0; x < 32; x += 8)
                *(bf16x8*)&dW[x] = *(const bf16x8*)(wp + x);
        }
        __syncthreads();   // (pp==0: also covers T-write)
        floatx4 acc2[2];
        #pragma unroll
        for (int j = 0; j < 2; j++) acc2[j] = (floatx4)0.f;
        #pragma unroll
        for (int kk = 0; kk < KB; kk += 32) {
            bf16x8 a0 = *(const bf16x8*)&T[wrow + lr][kk + quad * 8];
            bf16x8 b0 = *(const bf16x8*)&Ws[wn + lr     ][kk + quad * 8];
            bf16x8 b1 = *(const bf16x8*)&Ws[wn + 16 + lr][kk + quad * 8];
            acc2[0] = __builtin_amdgcn_mfma_f32_16x16x32_bf16(a0, b0, acc2[0], 0, 0, 0);
            acc2[1] = __builtin_amdgcn_mfma_f32_16x16x32_bf16(a0, b1, acc2[1], 0, 0, 0);
        }
        if (piece == 0) {
            #pragma unroll
            for (int j = 0; j < 2; j++) {
                int gn = c0 + wn + j * 16 + lr;
                float bb = b2[gn];
                #pragma unroll
                for (int rr = 0; rr < 4; rr++)
                    avvr[j][rr] = acc2[j][rr] + bb;
            }
        } else if (piece == 1) {
            #pragma unroll
            for (int j = 0; j < 2; j++) {
                int gn = c0 + wn + j * 16 + lr;
                float bb = b2[gn];
                #pragma unroll
                for (int rr = 0; rr < 4; rr++)
                    asvr[j][rr] = acc2[j][rr] + bb;
            }
        } else {
            // ass chunk: full node update + As s-deposit
            #pragma unroll
            for (int j = 0; j < 2; j++) {
                int gn = c0 + wn + j * 16 + lr;
                int f  = gn - 256;          // = part*64 + wn + j*16 + lr
                float bb = b2[gn];
                #pragma unroll
                for (int rr = 0; rr < 4; rr++) {
                    int row = wrow + quad * 4 + rr;
                    int gm = bm + row;
                    if (gm < M) {
                        float ass = acc2[j][rr] + bb;
                        float asv = asvr[j][rr];
                        float avv = avvr[j][rr];
                        int vb = gm * F3 + f;
                        float u0 = b2f(Uv[vb]);
                        float u1 = b2f(Uv[vb + FD]);
                        float u2 = b2f(Uv[vb + 2 * FD]);
                        float w0 = b2f(Vv[vb]);
                        float w1 = b2f(Vv[vb + FD]);
                        float w2 = b2f(Vv[vb + 2 * FD]);
                        float dot = u0 * w0 + u1 * w1 + u2 * w2;
                        int nb = gm * FD + f;
                        float so = s_mid[nb] + ass + asv * dot;
                        s_out[nb] = so;
                        As[row][f] = f2b(so);
                        float y0 = v_mid[vb]          + avv * u0;
                        float y1 = v_mid[vb + FD]     + avv * u1;
                        float y2 = v_mid[vb + 2 * FD] + avv * u2;
                        v_out[vb]          = y0;
                        v_out[vb + FD]     = y1;
                        v_out[vb + 2 * FD] = y2;
                        char* vpb = (char*)v_pk + (size_t)gm * (2 * F3);
                        *(u32*)(vpb + 4 * f) = pack2(y0, y1);
                        *(u16*)(vpb + 512 + 2 * f) = f2b(y2);
                    } else {
                        As[row][f] = 0;
                    }
                }
            }
        }
        __syncthreads();   // piece consumed (and As deposit visible) before restage
    }
    // As now holds this block's fresh s (bf16), 32 rows x 128 cols.

    if constexpr (!LAST) {
        // ---------------- appended mlp1 of next iteration (A = As, K=128)
        {
            #pragma unroll
            for (int h = 0; h < 2; h++) {
                int wr = r + h * 64;
                const u16* wp = N_W1 + (size_t)wr * KB + q * 32;
                u16* dW = &Ws[wr][q * 32];
                #pragma unroll
                for (int x = 0; x < 32; x += 8)
                    *(bf16x8*)&dW[x] = *(const bf16x8*)(wp + x);
            }
        }
        __syncthreads();
        #pragma unroll
        for (int j = 0; j < 4; j++) acc1[j] = (floatx4)0.f;
        #pragma unroll
        for (int kk = 0; kk < KB; kk += 32) {
            bf16x8 a0 = *(const bf16x8*)&As[wrow + lr][kk + quad * 8];
            #pragma unroll
            for (int j = 0; j < 4; j++) {
                bf16x8 b = *(const bf16x8*)&Ws[wn1 + j * 16 + lr][kk + quad * 8];
                acc1[j] = __builtin_amdgcn_mfma_f32_16x16x32_bf16(a0, b, acc1[j], 0, 0, 0);
            }
        }
        __syncthreads();   // Ws consumed -> T region writable
        #pragma unroll
        for (int j = 0; j < 4; j++) {
            int col = wn1 + j * 16 + lr;
            float bb = N_b1[col];
            #pragma unroll
            for (int rr = 0; rr < 4; rr++) {
                int row = wrow + quad * 4 + rr;
                float v = acc1[j][rr] + bb;
                v = v / (1.f + __expf(-v));
                T[row][col] = f2b(v);
            }
        }
        // GEMM2 (6 pieces of 64 cols into Ws[0..63])
        for (int pp = 0; pp < 6; pp++) {
            const int c0 = pp * 64;
            {
                const u16* wp = N_W2 + (size_t)(c0 + r) * KB + q * 32;
                u16* dW = &Ws[r][q * 32];
                #pragma unroll
                for (int x = 0; x < 32; x += 8)
                    *(bf16x8*)&dW[x] = *(const bf16x8*)(wp + x);
            }
            __syncthreads();   // (pp==0: also covers T-write)
            floatx4 acc2[2];
            #pragma unroll
            for (int j = 0; j < 2; j++) acc2[j] = (floatx4)0.f;
            #pragma unroll
            for (int kk = 0; kk < KB; kk += 32) {
                bf16x8 a0 = *(const bf16x8*)&T[wrow + lr][kk + quad * 8];
                bf16x8 b0 = *(const bf16x8*)&Ws[wn + lr     ][kk + quad * 8];
                bf16x8 b1 = *(const bf16x8*)&Ws[wn + 16 + lr][kk + quad * 8];
                acc2[0] = __builtin_amdgcn_mfma_f32_16x16x32_bf16(a0, b0, acc2[0], 0, 0, 0);
                acc2[1] = __builtin_amdgcn_mfma_f32_16x16x32_bf16(a0, b1, acc2[1], 0, 0, 0);
            }
            #pragma unroll
            for (int j = 0; j < 2; j++) {
                int gn = c0 + wn + j * 16 + lr;
                float bb = N_b2[gn];
                #pragma unroll
                for (int rr = 0; rr < 4; rr++) {
                    int gm = bm + wrow + quad * 4 + rr;
                    if (gm < M) {
                        u16 val = f2b(acc2[j][rr] + bb);
                        int off = (gn < 256) ? ((gn & 127) * 2 + (gn >> 7))
                                             : (256 + (gn & 127));
                        a_pk[(size_t)gm * F3 + off] = val;
                    }
                }
            }
            __syncthreads();
        }
    } else {
        // ---------------- appended final head: t = silu(s@ow1^T+ob1);
        // per-node dot with ow2 -> atomicAdd into per-molecule out (mol_reduce fused).
        {
            #pragma unroll
            for (int h = 0; h < 2; h++) {
                int wr = r + h * 64;
                const u16* wp = H_W1 + (size_t)wr * KB + q * 32;
                u16* dW = &Ws[wr][q * 32];
                #pragma unroll
                for (int x = 0; x < 32; x += 8)
                    *(bf16x8*)&dW[x] = *(const bf16x8*)(wp + x);
            }
        }
        __syncthreads();
        #pragma unroll
        for (int j = 0; j < 4; j++) acc1[j] = (floatx4)0.f;
        #pragma unroll
        for (int kk = 0; kk < KB; kk += 32) {
            bf16x8 a0 = *(const bf16x8*)&As[wrow + lr][kk + quad * 8];
            #pragma unroll
            for (int j = 0; j < 4; j++) {
                bf16x8 b = *(const bf16x8*)&Ws[wn1 + j * 16 + lr][kk + quad * 8];
                acc1[j] = __builtin_amdgcn_mfma_f32_16x16x32_bf16(a0, b, acc1[j], 0, 0, 0);
            }
        }
        __syncthreads();   // Ws + As fully consumed
        float* ow2s = (float*)&As[0][0];   // 128 f32 (As dead)
        if (tid < KB) ow2s[tid] = ow2[tid];
        #pragma unroll
        for (int j = 0; j < 4; j++) {
            int col = wn1 + j * 16 + lr;
            float bb = H_b1[col];
            #pragma unroll
            for (int rr = 0; rr < 4; rr++) {
                int row = wrow + quad * 4 + rr;
                float v = acc1[j][rr] + bb;
                v = v / (1.f + __expf(-v));
                T[row][col] = f2b(v);      // bf16 t in Ws[64..]
            }
        }
        __syncthreads();
        // dot with ow2: 8 threads per node, 16 cols each, shfl-reduce within 8-lane group
        int nl = tid >> 3, seg = tid & 7;
        float v = 0.f;
        #pragma unroll
        for (int x = 0; x < 16; x++) {
            int col = seg * 16 + x;
            v += b2f(T[nl][col]) * ow2s[col];
        }
        v += __shfl_down(v, 4);
        v += __shfl_down(v, 2);
        v += __shfl_down(v, 1);
        if (seg == 0) {
            int gm = bm + nl;
            if (gm < M) atomicAdd(&outp[gidx[gm]], v + ob2[0]);
        }
    }
}

// ---------------------------------------------------------------- launch
extern "C" void kernel_launch(void* const* d_in, const int* in_sizes, int n_in,
                              void* d_out, int out_size, void* d_ws, size_t ws_size,
                              hipStream_t stream)
{
    const int*   z     = (const int*)d_in[0];
    const int*   graph = (const int*)d_in[1];
    const float* dist  = (const float*)d_in[2];
    const float* sense = (const float*)d_in[3];
    const int*   gidx  = (const int*)d_in[4];
    const float* emb   = (const float*)d_in[5];
    const float* mw1   = (const float*)d_in[6];
    const float* mb1   = (const float*)d_in[7];
    const float* mw2   = (const float*)d_in[8];
    const float* mb2   = (const float*)d_in[9];
    const float* ew    = (const float*)d_in[10];
    const float* eb    = (const float*)d_in[11];
    const float* uw    = (const float*)d_in[12];
    const float* vw    = (const float*)d_in[13];
    const float* aw1   = (const float*)d_in[14];
    const float* ab1   = (const float*)d_in[15];
    const float* aw2   = (const float*)d_in[16];
    const float* ab2   = (const float*)d_in[17];
    const float* ow1   = (const float*)d_in[18];
    const float* ob1   = (const float*)d_in[19];
    const float* ow2   = (const float*)d_in[20];
    const float* ob2   = (const float*)d_in[21];
    float* out = (float*)d_out;

    // ---- workspace carve-up ----
    float* W = (float*)d_ws;
    float* s_a    = W; W += (size_t)NN * FD;
    float* s_b    = W; W += (size_t)NN * FD;
    float* v_a    = W; W += (size_t)NN * F3;
    float* v_b    = W; W += (size_t)NN * F3;
    float* cut_p  = W; W += (size_t)NE;
    float* sns_p  = W; W += (size_t)NE * 3;
    float* nodeval= W; W += (size_t)NN;     // unused (layout stability)
    u16* U = (u16*)W;
    u16* sbf_a = U; U += (size_t)NN * FD;
    u16* sbf_b = U; U += (size_t)NN * FD;
    u16* vbf_b = U; U += (size_t)NN * F3;
    u16* a_pk  = U; U += (size_t)NN * F3;
    u16* v_pk  = U; U += (size_t)NN * F3;
    u16* h_bf  = U; U += (size_t)NN * F2;   // unused (layout stability)
    u16* a2_bf = U; U += (size_t)NN * F3;   // unused (layout stability)
    u16* Uv_bf = U; U += (size_t)NN * F3;
    u16* Vv_bf = U; U += (size_t)NN * F3;
    u16* rbf_bf= U; U += (size_t)NE * 32;
    u16* ewb   = U; U += (size_t)NITER * F3 * 32;
    u16* wb    = U; U += 557056;
    int* ip = (int*)U;
    int* row_ptr   = ip; ip += NN + 1;
    int* cnt       = ip; ip += NN;
    int* cursor    = ip; ip += NN;
    int* edge_list = ip; ip += NE;
    int* dst_p     = ip; ip += NE;

    // bf16 weight table offsets
    u16* wb_mw1 = wb;            // 3*128*128
    u16* wb_mw2 = wb + 49152;    // 3*384*128
    u16* wb_uw  = wb + 196608;   // 3*128*128
    u16* wb_vw  = wb + 245760;   // 3*128*128
    u16* wb_aw1 = wb + 294912;   // 3*128*256
    u16* wb_aw2 = wb + 393216;   // 3*384*128
    u16* wb_ow1 = wb + 540672;   // 128*128

    const int TB = 256;
    dim3 b256(TB);

    // --- precompute ---
    init_all_kernel<<<dim3((NN * F3 + TB - 1) / TB), b256, 0, stream>>>(
        mw1, 49152, mw2, 147456, uw, 49152, vw, 49152, aw1, 98304, aw2, 147456,
        ow1, 16384, wb, ew, ewb, z, emb, s_a, sbf_a, v_a, (int*)v_pk, cnt, out);
    csr_count_kernel<<<dim3((NE + TB - 1) / TB), b256, 0, stream>>>(graph, cnt);
    csr_scan_kernel<<<dim3(1), dim3(1024), 0, stream>>>(cnt, row_ptr, cursor);
    csr_scatter_kernel<<<dim3((NE + TB - 1) / TB), b256, 0, stream>>>(graph, cursor, edge_list);
    edge_stream_kernel<<<dim3((NE + TB - 1) / TB), b256, 0, stream>>>(
        edge_list, graph, dist, sense, rbf_bf, cut_p, sns_p, dst_p);

    dim3 gM2((NN + BM2 - 1) / BM2);             // node kernels (BM=32, 625 blocks)
    dim3 gUV((3 * NN + BM2 - 1) / BM2);         // gemm_uv (BM=32, 1875 blocks)

    // iter-0 message MLP (later iterations' mlp1 are fused into mlp2_update_next)
    mlp1_kernel<<<gM2, b256, 0, stream>>>(sbf_a,
        wb_mw1, mb1, wb_mw2, mb2, a_pk, NN);

    for (int i = 0; i < NITER; i++) {
        edge_mfma_kernel<<<dim3(NN), b256, 0, stream>>>(
            rbf_bf, cut_p, sns_p, dst_p,
            ewb + (size_t)i * F3 * 32, eb + (size_t)i * F3,
            a_pk, s_a, v_a, v_pk, row_ptr, s_b, sbf_b, v_b, vbf_b);
        gemm_uv<<<gUV, b256, 0, stream>>>(vbf_b, wb_uw + (size_t)i * FD * FD,
            wb_vw + (size_t)i * FD * FD, Uv_bf, Vv_bf, 3 * NN);
        if (i < NITER - 1) {
            mlp2_update_next_kernel<false><<<gM2, b256, 0, stream>>>(
                sbf_b, s_b, v_b, Uv_bf, Vv_bf,
                wb_aw1 + (size_t)i * FD * F2, ab1 + (size_t)i * FD,
                wb_aw2 + (size_t)i * F3 * FD, ab2 + (size_t)i * F3,
                s_a, v_a, v_pk,
                wb_mw1 + (size_t)(i + 1) * FD * FD, mb1 + (size_t)(i + 1) * FD,
                wb_mw2 + (size_t)(i + 1) * F3 * FD, mb2 + (size_t)(i + 1) * F3, a_pk,
                nullptr, nullptr, nullptr, nullptr, nullptr, nullptr, NN);
        } else {
            mlp2_update_next_kernel<true><<<gM2, b256, 0, stream>>>(
                sbf_b, s_b, v_b, Uv_bf, Vv_bf,
                wb_aw1 + (size_t)i * FD * F2, ab1 + (size_t)i * FD,
                wb_aw2 + (size_t)i * F3 * FD, ab2 + (size_t)i * F3,
                s_a, v_a, v_pk,
                nullptr, nullptr, nullptr, nullptr, nullptr,
                wb_ow1, ob1, ow2, ob2, gidx, out, NN);
        }
    }
}

// Round 11
// 850.660 us; speedup vs baseline: 1.0986x; 1.0986x over previous
//
#include <hip/hip_runtime.h>
#include <math.h>

// Problem constants
#define NN 20000
#define NE 320000
#define FD 128
#define RBFN 20
#define RC_ 5.0f
#define NITER 3
#define NMOL 64
#define F3 384
#define F2 256
#define PI_ 3.14159265358979323846f
#define KB 128
#define LPAD 8
#define SDS 392   // u16 stride per sdrep edge row (384 + 8 pad)
#define BM2 32    // node-path rows/block (more blocks/CU — validated lever, r9)

typedef __attribute__((ext_vector_type(8))) short  bf16x8;
typedef __attribute__((ext_vector_type(4))) float  floatx4;
typedef unsigned short u16;
typedef unsigned int   u32;

__device__ __forceinline__ u16 f2b(float x) {
    union { float f; unsigned int u; } v; v.f = x;
    unsigned int u = v.u;
    return (u16)((u + 0x7fffu + ((u >> 16) & 1u)) >> 16);   // RNE
}
__device__ __forceinline__ float b2f(u16 x) {
    union { unsigned int u; float f; } v; v.u = ((unsigned int)x) << 16;
    return v.f;
}
__device__ __forceinline__ float blo(u32 w) {
    union { unsigned int u; float f; } v; v.u = w << 16; return v.f;
}
__device__ __forceinline__ float bhi(u32 w) {
    union { unsigned int u; float f; } v; v.u = w & 0xffff0000u; return v.f;
}
__device__ __forceinline__ u32 pack2(float a, float b) {
    return (u32)f2b(a) | ((u32)f2b(b) << 16);
}

// ---------------------------------------------------------------- fused one-time init
__global__ __launch_bounds__(256) void init_all_kernel(
    const float* s0, int n0, const float* s1, int n1, const float* s2, int n2,
    const float* s3, int n3, const float* s4, int n4, const float* s5, int n5,
    const float* s6, int n6, u16* __restrict__ wdst,
    const float* __restrict__ ew, u16* __restrict__ ewb,
    const int* __restrict__ z, const float* __restrict__ emb,
    float* __restrict__ s, u16* __restrict__ sbf,
    float* __restrict__ v_a, int* __restrict__ v_pk_i, int* __restrict__ cnt)
{
    int idx = blockIdx.x * 256 + threadIdx.x;
    if (idx < NN * F3) v_a[idx] = 0.f;
    if (idx < NN * F3 / 2) v_pk_i[idx] = 0;
    if (idx < NN) cnt[idx] = 0;
    if (idx < NN * FD) {
        int n = idx >> 7, f = idx & 127;
        float v = emb[z[n] * FD + f];
        s[idx] = v; sbf[idx] = f2b(v);
    }
    if (idx < NITER * F3 * 32) {
        int k = idx & 31;
        int row = idx >> 5;
        ewb[idx] = (k < RBFN) ? f2b(ew[row * RBFN + k]) : (u16)0;
    }
    {
        int w = idx;
        u16* dst = wdst;
        if (w < n0) { dst[w] = f2b(s0[w]); return; } w -= n0; dst += n0;
        if (w < n1) { dst[w] = f2b(s1[w]); return; } w -= n1; dst += n1;
        if (w < n2) { dst[w] = f2b(s2[w]); return; } w -= n2; dst += n2;
        if (w < n3) { dst[w] = f2b(s3[w]); return; } w -= n3; dst += n3;
        if (w < n4) { dst[w] = f2b(s4[w]); return; } w -= n4; dst += n4;
        if (w < n5) { dst[w] = f2b(s5[w]); return; } w -= n5; dst += n5;
        if (w < n6) { dst[w] = f2b(s6[w]); }
    }
}

// ---------------------------------------------------------------- CSR build
__global__ __launch_bounds__(256) void csr_count_kernel(const int* __restrict__ graph,
    int* __restrict__ cnt)
{
    int e = blockIdx.x * 256 + threadIdx.x;
    if (e >= NE) return;
    atomicAdd(&cnt[graph[2 * e]], 1);
}

__global__ __launch_bounds__(1024) void csr_scan_kernel(const int* __restrict__ cnt,
    int* __restrict__ row_ptr, int* __restrict__ cursor)
{
    __shared__ int sd[1024];
    int tid = threadIdx.x;
    const int chunk = (NN + 1023) / 1024;
    int start = tid * chunk;
    int end = start + chunk; if (end > NN) end = NN;
    int sum = 0;
    for (int j = start; j < end; j++) sum += cnt[j];
    sd[tid] = sum;
    __syncthreads();
    for (int off = 1; off < 1024; off <<= 1) {
        int v = 0;
        if (tid >= off) v = sd[tid - off];
        __syncthreads();
        if (tid >= off) sd[tid] += v;
        __syncthreads();
    }
    int run = (tid == 0) ? 0 : sd[tid - 1];
    for (int j = start; j < end; j++) {
        row_ptr[j] = run;
        cursor[j]  = run;
        run += cnt[j];
    }
    if (tid == 0) row_ptr[NN] = NE;
}

__global__ __launch_bounds__(256) void csr_scatter_kernel(const int* __restrict__ graph,
    int* __restrict__ cursor, int* __restrict__ edge_list)
{
    int e = blockIdx.x * 256 + threadIdx.x;
    if (e >= NE) return;
    int p = atomicAdd(&cursor[graph[2 * e]], 1);
    edge_list[p] = e;
}

// Permuted edge streams in CSR order; Chebyshev sin recurrence; vectorized rbf stores.
__global__ __launch_bounds__(256) void edge_stream_kernel(
    const int* __restrict__ edge_list, const int* __restrict__ graph,
    const float* __restrict__ dist, const float* __restrict__ sense,
    u16* __restrict__ rbf_bf, float* __restrict__ cut_p,
    float* __restrict__ sense_p, int* __restrict__ dst_p)
{
    int j = blockIdx.x * 256 + threadIdx.x;
    if (j >= NE) return;
    int e = edge_list[j];
    float d = dist[e];
    float inv = 1.f / d;
    float base = PI_ * d / RC_;
    float s1, c1;
    __sincosf(base, &s1, &c1);
    float twoc = c1 + c1;
    u16 tmp[32];
    float sprev = 0.f, scur = s1;
    #pragma unroll
    for (int k = 0; k < RBFN; k++) {
        tmp[k] = f2b(scur * inv);
        float snext = twoc * scur - sprev;
        sprev = scur; scur = snext;
    }
    #pragma unroll
    for (int k = RBFN; k < 32; k++) tmp[k] = 0;
    u16* rb = rbf_bf + (size_t)j * 32;
    #pragma unroll
    for (int x = 0; x < 32; x += 8)
        *(bf16x8*)&rb[x] = *(const bf16x8*)&tmp[x];
    cut_p[j] = 0.5f * (c1 + 1.f) * (d < RC_ ? 1.f : 0.f);
    dst_p[j] = graph[2 * e + 1];
    sense_p[3 * j + 0] = sense[3 * e + 0];
    sense_p[3 * j + 1] = sense[3 * e + 1];
    sense_p[3 * j + 2] = sense[3 * e + 2];
}

// ---------------------------------------------------------------- iter-0 message MLP (BM=32)
__global__ __launch_bounds__(256) void mlp1_kernel(const u16* __restrict__ A,
    const u16* __restrict__ W1, const float* __restrict__ b1,
    const u16* __restrict__ W2, const float* __restrict__ b2,
    u16* __restrict__ Ob, int M)
{
    __shared__ u16 As[BM2][KB + LPAD];
    __shared__ u16 Ws[128][KB + LPAD];
    u16 (*T)[KB + LPAD] = &Ws[64];     // alias: valid only after GEMM1 consumed Ws
    const int bm = blockIdx.x * BM2;
    const int tid = threadIdx.x;
    const int wave = tid >> 6, lane = tid & 63;
    const int wrow = (wave >> 1) * 16;
    const int wn1  = (wave & 1) * 64;
    const int wn   = (wave & 1) * 32;
    const int quad = lane >> 4, lr = lane & 15;
    const int r = tid >> 2, q = tid & 3;
    const int r3 = tid >> 3, c16 = (tid & 7) * 16;

    floatx4 acc1[4];
    #pragma unroll
    for (int j = 0; j < 4; j++) acc1[j] = (floatx4)0.f;

    {
        int gm = bm + r3;
        u16* dA = &As[r3][c16];
        if (gm < M) {
            const u16* ap = A + (size_t)gm * KB + c16;
            *(bf16x8*)&dA[0] = *(const bf16x8*)(ap);
            *(bf16x8*)&dA[8] = *(const bf16x8*)(ap + 8);
        } else {
            *(bf16x8*)&dA[0] = (bf16x8)0;
            *(bf16x8*)&dA[8] = (bf16x8)0;
        }
        #pragma unroll
        for (int h = 0; h < 2; h++) {
            int wr = r + h * 64;
            const u16* wp = W1 + (size_t)wr * KB + q * 32;
            u16* dW = &Ws[wr][q * 32];
            #pragma unroll
            for (int x = 0; x < 32; x += 8)
                *(bf16x8*)&dW[x] = *(const bf16x8*)(wp + x);
        }
    }
    __syncthreads();
    #pragma unroll
    for (int kk = 0; kk < KB; kk += 32) {
        bf16x8 a0 = *(const bf16x8*)&As[wrow + lr][kk + quad * 8];
        #pragma unroll
        for (int j = 0; j < 4; j++) {
            bf16x8 b = *(const bf16x8*)&Ws[wn1 + j * 16 + lr][kk + quad * 8];
            acc1[j] = __builtin_amdgcn_mfma_f32_16x16x32_bf16(a0, b, acc1[j], 0, 0, 0);
        }
    }
    __syncthreads();   // Ws consumed -> T region writable
    #pragma unroll
    for (int j = 0; j < 4; j++) {
        int col = wn1 + j * 16 + lr;
        float bb = b1[col];
        #pragma unroll
        for (int rr = 0; rr < 4; rr++) {
            int row = wrow + quad * 4 + rr;
            float v = acc1[j][rr] + bb;
            v = v / (1.f + __expf(-v));
            T[row][col] = f2b(v);
        }
    }
    for (int pp = 0; pp < 6; pp++) {
        const int c0 = pp * 64;
        {
            const u16* wp = W2 + (size_t)(c0 + r) * KB + q * 32;
            u16* dW = &Ws[r][q * 32];
            #pragma unroll
            for (int x = 0; x < 32; x += 8)
                *(bf16x8*)&dW[x] = *(const bf16x8*)(wp + x);
        }
        __syncthreads();   // (pp==0: also covers T-write)
        floatx4 acc2[2];
        #pragma unroll
        for (int j = 0; j < 2; j++) acc2[j] = (floatx4)0.f;
        #pragma unroll
        for (int kk = 0; kk < KB; kk += 32) {
            bf16x8 a0 = *(const bf16x8*)&T[wrow + lr][kk + quad * 8];
            bf16x8 b0 = *(const bf16x8*)&Ws[wn + lr     ][kk + quad * 8];
            bf16x8 b1 = *(const bf16x8*)&Ws[wn + 16 + lr][kk + quad * 8];
            acc2[0] = __builtin_amdgcn_mfma_f32_16x16x32_bf16(a0, b0, acc2[0], 0, 0, 0);
            acc2[1] = __builtin_amdgcn_mfma_f32_16x16x32_bf16(a0, b1, acc2[1], 0, 0, 0);
        }
        #pragma unroll
        for (int j = 0; j < 2; j++) {
            int gn = c0 + wn + j * 16 + lr;
            float bb = b2[gn];
            #pragma unroll
            for (int rr = 0; rr < 4; rr++) {
                int gm = bm + wrow + quad * 4 + rr;
                if (gm < M) {
                    u16 val = f2b(acc2[j][rr] + bb);
                    int off = (gn < 256) ? ((gn & 127) * 2 + (gn >> 7))
                                         : (256 + (gn & 127));
                    Ob[(size_t)gm * F3 + off] = val;
                }
            }
        }
        __syncthreads();
    }
}

// Dual GEMM: U = A@Wu^T, V = A@Wv^T (K=128, Nc=128). bf16 outs. BM=32 re-tile (1875 blocks).
__global__ __launch_bounds__(256) void gemm_uv(const u16* __restrict__ A,
    const u16* __restrict__ Wu, const u16* __restrict__ Wv,
    u16* __restrict__ U, u16* __restrict__ V, int M)
{
    __shared__ u16 As[BM2][KB + LPAD];
    __shared__ u16 Bu[64][KB + LPAD];
    __shared__ u16 Bv[64][KB + LPAD];
    const int bm = blockIdx.x * BM2;
    const int tid = threadIdx.x;
    const int r = tid >> 2;
    const int q = tid & 3;
    const int r3 = tid >> 3, c16 = (tid & 7) * 16;
    const int wave = tid >> 6;
    const int lane = tid & 63;
    const int wrow = (wave >> 1) * 16;
    const int wn = (wave & 1) * 32;
    const int quad = lane >> 4;
    const int lr = lane & 15;

    {
        int gm = bm + r3;
        u16* dA = &As[r3][c16];
        if (gm < M) {
            const u16* ap = A + (size_t)gm * KB + c16;
            *(bf16x8*)&dA[0] = *(const bf16x8*)(ap);
            *(bf16x8*)&dA[8] = *(const bf16x8*)(ap + 8);
        } else {
            *(bf16x8*)&dA[0] = (bf16x8)0;
            *(bf16x8*)&dA[8] = (bf16x8)0;
        }
    }

    #pragma unroll
    for (int bn = 0; bn < FD; bn += 64) {
        {
            int gn = bn + r;
            const u16* up = Wu + (size_t)gn * KB + q * 32;
            const u16* vp = Wv + (size_t)gn * KB + q * 32;
            u16* dU = &Bu[r][q * 32];
            u16* dV = &Bv[r][q * 32];
            #pragma unroll
            for (int x = 0; x < 32; x += 8) {
                *(bf16x8*)&dU[x] = *(const bf16x8*)(up + x);
                *(bf16x8*)&dV[x] = *(const bf16x8*)(vp + x);
            }
        }
        __syncthreads();
        floatx4 au[2], av[2];
        #pragma unroll
        for (int j = 0; j < 2; j++) { au[j] = (floatx4)0.f; av[j] = (floatx4)0.f; }
        #pragma unroll
        for (int kk = 0; kk < KB; kk += 32) {
            bf16x8 a0 = *(const bf16x8*)&As[wrow + lr][kk + quad * 8];
            bf16x8 u0 = *(const bf16x8*)&Bu[wn + lr     ][kk + quad * 8];
            bf16x8 u1 = *(const bf16x8*)&Bu[wn + 16 + lr][kk + quad * 8];
            bf16x8 v0 = *(const bf16x8*)&Bv[wn + lr     ][kk + quad * 8];
            bf16x8 v1 = *(const bf16x8*)&Bv[wn + 16 + lr][kk + quad * 8];
            au[0] = __builtin_amdgcn_mfma_f32_16x16x32_bf16(a0, u0, au[0], 0, 0, 0);
            au[1] = __builtin_amdgcn_mfma_f32_16x16x32_bf16(a0, u1, au[1], 0, 0, 0);
            av[0] = __builtin_amdgcn_mfma_f32_16x16x32_bf16(a0, v0, av[0], 0, 0, 0);
            av[1] = __builtin_amdgcn_mfma_f32_16x16x32_bf16(a0, v1, av[1], 0, 0, 0);
        }
        #pragma unroll
        for (int j = 0; j < 2; j++) {
            int gn = bn + wn + j * 16 + lr;
            #pragma unroll
            for (int rr = 0; rr < 4; rr++) {
                int gm = bm + wrow + quad * 4 + rr;
                if (gm < M) {
                    U[(size_t)gm * FD + gn] = f2b(au[j][rr]);
                    V[(size_t)gm * FD + gn] = f2b(av[j][rr]);
                }
            }
        }
        __syncthreads();   // Bu/Bv fully consumed before restage
    }
}

// ---------------------------------------------------------------- edge aggregate (MFMA dist_rep)
// 256 threads/node — PROVEN 138µs form, do not modify.
__global__ __launch_bounds__(256) void edge_mfma_kernel(
    const u16* __restrict__ rbf_bf, const float* __restrict__ cut_p,
    const float* __restrict__ sense_p, const int* __restrict__ dst_p,
    const u16* __restrict__ ewb, const float* __restrict__ eb,
    const u16* __restrict__ a_pk, const float* __restrict__ s_in,
    const float* __restrict__ v_in, const u16* __restrict__ v_pk,
    const int* __restrict__ row_ptr,
    float* __restrict__ s_out, u16* __restrict__ s_obf,
    float* __restrict__ v_out, u16* __restrict__ v_obf)
{
    __shared__ u16   sdrep[16 * SDS];
    __shared__ float scut[16];
    __shared__ float ssen[16][4];
    __shared__ int   sdst[16];
    __shared__ float red[4 * 128];

    const int n = blockIdx.x;
    const int tid = threadIdx.x;
    const int wave = tid >> 6;
    const int lane = tid & 63;
    const int quad = lane >> 4;
    const int lr = lane & 15;
    const int f = tid & 127;
    const int half = tid >> 7;

    int beg = row_ptr[n], end = row_ptr[n + 1];
    float accs = 0.f, accv0 = 0.f, accv1 = 0.f, accv2 = 0.f;

    for (int t0 = beg; t0 < end; t0 += 16) {
        int cnt = end - t0; if (cnt > 16) cnt = 16;
        __syncthreads();
        if (tid < 16) {
            scut[tid] = (tid < cnt) ? cut_p[t0 + tid] : 0.f;
            sdst[tid] = (tid < cnt) ? dst_p[t0 + tid] : 0;
        }
        if (tid >= 64 && tid < 64 + 3 * cnt) {
            int x = tid - 64;
            ssen[x / 3][x % 3] = sense_p[3 * t0 + x];
        }
        bf16x8 afrag;
        int ge = t0 + lr;
        if (ge < end) afrag = *(const bf16x8*)&rbf_bf[(size_t)ge * 32 + quad * 8];
        else          afrag = (bf16x8)0;
        floatx4 dacc[6];
        #pragma unroll
        for (int nt = 0; nt < 6; nt++) {
            int nrow = (wave * 6 + nt) * 16 + lr;
            bf16x8 bfrag = *(const bf16x8*)&ewb[(size_t)nrow * 32 + quad * 8];
            dacc[nt] = __builtin_amdgcn_mfma_f32_16x16x32_bf16(afrag, bfrag, (floatx4)0.f, 0, 0, 0);
        }
        __syncthreads();
        #pragma unroll
        for (int nt = 0; nt < 6; nt++) {
            int ncol = (wave * 6 + nt) * 16 + lr;
            float ebn = eb[ncol];
            #pragma unroll
            for (int rr = 0; rr < 4; rr++) {
                int e = quad * 4 + rr;
                sdrep[e * SDS + ncol] = f2b((dacc[nt][rr] + ebn) * scut[e]);
            }
        }
        __syncthreads();
        int nh = cnt - half * 8; if (nh > 8) nh = 8;
        for (int k = 0; k < nh; k++) {
            int e = half * 8 + k;
            int dst = sdst[e];
            const u16* sr = &sdrep[e * SDS];
            float drv = b2f(sr[f]);
            float drs = b2f(sr[FD + f]);
            float drd = b2f(sr[2 * FD + f]);
            const u16* ar = a_pk + (size_t)dst * F3;
            u32 ap = *(const u32*)(ar + f * 2);
            float rv = b2f((u16)(ap & 0xffff)) * drv;
            float rs = b2f((u16)(ap >> 16))    * drs;
            float rd = b2f(ar[256 + f])        * drd;
            accs += rs;
            const u16* vr = v_pk + (size_t)dst * F3;
            u32 vp = *(const u32*)(vr + f * 2);
            accv0 += b2f((u16)(vp & 0xffff)) * rv + ssen[e][0] * rd;
            accv1 += b2f((u16)(vp >> 16))    * rv + ssen[e][1] * rd;
            accv2 += b2f(vr[256 + f])        * rv + ssen[e][2] * rd;
        }
    }
    __syncthreads();
    if (half == 1) {
        red[f] = accs; red[128 + f] = accv0; red[256 + f] = accv1; red[384 + f] = accv2;
    }
    __syncthreads();
    if (half == 0) {
        accs  += red[f];       accv0 += red[128 + f];
        accv1 += red[256 + f]; accv2 += red[384 + f];
        int nb = n * FD + f;
        float so = s_in[nb] + 2.f * accs;
        s_out[nb] = so; s_obf[nb] = f2b(so);
        int vb = n * F3 + f;
        float w0 = v_in[vb]           + 2.f * accv0;
        float w1 = v_in[vb + FD]      + 2.f * accv1;
        float w2 = v_in[vb + 2 * FD]  + 2.f * accv2;
        v_out[vb]          = w0; v_obf[vb]          = f2b(w0);
        v_out[vb + FD]     = w1; v_obf[vb + FD]     = f2b(w1);
        v_out[vb + 2 * FD] = w2; v_obf[vb + 2 * FD] = f2b(w2);
    }
}

// ---------------------------------------------------------------- fused mlp2 + build_h + update + NEXT
// BM=32 (625 blocks). T aliased onto Ws[64..127]; ass chunk does node update inline and
// deposits fresh s into As.  LAST=false appends next mlp1; LAST=true appends head writing
// nodeval (plain stores — atomicAdd-to-64-buckets variant measured 174µs vs ~80, reverted r11).
template<bool LAST>
__global__ __launch_bounds__(256) void mlp2_update_next_kernel(
    const u16* __restrict__ sbf_mid, const float* __restrict__ s_mid,
    const float* __restrict__ v_mid,
    const u16* __restrict__ Uv, const u16* __restrict__ Vv,
    const u16* __restrict__ W1, const float* __restrict__ b1,
    const u16* __restrict__ W2, const float* __restrict__ b2,
    float* __restrict__ s_out,
    float* __restrict__ v_out, u16* __restrict__ v_pk,
    const u16* __restrict__ N_W1, const float* __restrict__ N_b1,
    const u16* __restrict__ N_W2, const float* __restrict__ N_b2,
    u16* __restrict__ a_pk,
    const u16* __restrict__ H_W1, const float* __restrict__ H_b1,
    const float* __restrict__ ow2, const float* __restrict__ ob2,
    float* __restrict__ nodeval, int M)
{
    __shared__ u16 As[BM2][KB + LPAD];
    __shared__ u16 Ws[128][KB + LPAD];
    u16 (*T)[KB + LPAD] = &Ws[64];     // alias: valid only after GEMM1 consumed Ws
    const int bm = blockIdx.x * BM2;
    const int tid = threadIdx.x;
    const int wave = tid >> 6, lane = tid & 63;
    const int wrow = (wave >> 1) * 16;      // 0 or 16
    const int wn1  = (wave & 1) * 64;       // GEMM1 col-half
    const int wn   = (wave & 1) * 32;       // GEMM2 col-half
    const int quad = lane >> 4, lr = lane & 15;
    const int r = tid >> 2, q = tid & 3;    // Ws staging (128 rows)
    const int r3 = tid >> 3, c16 = (tid & 7) * 16;  // As staging (32 rows x 128 cols)

    floatx4 acc1[4];
    #pragma unroll
    for (int j = 0; j < 4; j++) acc1[j] = (floatx4)0.f;

    // ---- GEMM1, ko chunk 0: A cols = s_mid bf16
    {
        int gm = bm + r3;
        u16* dA = &As[r3][c16];
        if (gm < M) {
            const u16* ap = sbf_mid + (size_t)gm * FD + c16;
            *(bf16x8*)&dA[0] = *(const bf16x8*)(ap);
            *(bf16x8*)&dA[8] = *(const bf16x8*)(ap + 8);
        } else {
            *(bf16x8*)&dA[0] = (bf16x8)0;
            *(bf16x8*)&dA[8] = (bf16x8)0;
        }
        #pragma unroll
        for (int h = 0; h < 2; h++) {
            int wr = r + h * 64;
            const u16* wp = W1 + (size_t)wr * F2 + q * 32;
            u16* dW = &Ws[wr][q * 32];
            #pragma unroll
            for (int x = 0; x < 32; x += 8)
                *(bf16x8*)&dW[x] = *(const bf16x8*)(wp + x);
        }
    }
    __syncthreads();
    #pragma unroll
    for (int kk = 0; kk < KB; kk += 32) {
        bf16x8 a0 = *(const bf16x8*)&As[wrow + lr][kk + quad * 8];
        #pragma unroll
        for (int j = 0; j < 4; j++) {
            bf16x8 b = *(const bf16x8*)&Ws[wn1 + j * 16 + lr][kk + quad * 8];
            acc1[j] = __builtin_amdgcn_mfma_f32_16x16x32_bf16(a0, b, acc1[j], 0, 0, 0);
        }
    }
    __syncthreads();
    // ---- GEMM1, ko chunk 1: A cols = |Vv| computed inline (build_h fused)
    {
        int gm = bm + r3;
        u16* dA = &As[r3][c16];
        if (gm < M) {
            const u16* vvp = Vv + (size_t)gm * F3 + c16;
            #pragma unroll
            for (int t = 0; t < 2; t++) {
                bf16x8 c0 = *(const bf16x8*)(vvp + t * 8);
                bf16x8 c1 = *(const bf16x8*)(vvp + FD + t * 8);
                bf16x8 c2 = *(const bf16x8*)(vvp + 2 * FD + t * 8);
                #pragma unroll
                for (int x = 0; x < 8; x++) {
                    float a = b2f((u16)c0[x]);
                    float b = b2f((u16)c1[x]);
                    float c = b2f((u16)c2[x]);
                    dA[t * 8 + x] = f2b(sqrtf(a * a + b * b + c * c));
                }
            }
        } else {
            *(bf16x8*)&dA[0] = (bf16x8)0;
            *(bf16x8*)&dA[8] = (bf16x8)0;
        }
        #pragma unroll
        for (int h = 0; h < 2; h++) {
            int wr = r + h * 64;
            const u16* wp = W1 + (size_t)wr * F2 + KB + q * 32;
            u16* dW = &Ws[wr][q * 32];
            #pragma unroll
            for (int x = 0; x < 32; x += 8)
                *(bf16x8*)&dW[x] = *(const bf16x8*)(wp + x);
        }
    }
    __syncthreads();
    #pragma unroll
    for (int kk = 0; kk < KB; kk += 32) {
        bf16x8 a0 = *(const bf16x8*)&As[wrow + lr][kk + quad * 8];
        #pragma unroll
        for (int j = 0; j < 4; j++) {
            bf16x8 b = *(const bf16x8*)&Ws[wn1 + j * 16 + lr][kk + quad * 8];
            acc1[j] = __builtin_amdgcn_mfma_f32_16x16x32_bf16(a0, b, acc1[j], 0, 0, 0);
        }
    }
    __syncthreads();   // all MFMAs done reading Ws -> T region writable
    // T = silu(acc1 + b1) as bf16  (rows 0..31 of Ws[64..])
    #pragma unroll
    for (int j = 0; j < 4; j++) {
        int col = wn1 + j * 16 + lr;
        float bb = b1[col];
        #pragma unroll
        for (int rr = 0; rr < 4; rr++) {
            int row = wrow + quad * 4 + rr;
            float v = acc1[j][rr] + bb;
            v = v / (1.f + __expf(-v));
            T[row][col] = f2b(v);
        }
    }

    // ---- GEMM2: pieces staged into Ws[0..63]; order (avv,asv,ass) per f-half.
    float avvr[2][4], asvr[2][4];
    #pragma unroll
    for (int pp = 0; pp < 6; pp++) {
        const int part  = pp / 3;
        const int piece = pp % 3;
        const int c0 = piece * 128 + part * 64;
        {
            const u16* wp = W2 + (size_t)(c0 + r) * KB + q * 32;
            u16* dW = &Ws[r][q * 32];
            #pragma unroll
            for (int x = 0; x < 32; x += 8)
                *(bf16x8*)&dW[x] = *(const bf16x8*)(wp + x);
        }
        __syncthreads();   // (pp==0: also covers T-write)
        floatx4 acc2[2];
        #pragma unroll
        for (int j = 0; j < 2; j++) acc2[j] = (floatx4)0.f;
        #pragma unroll
        for (int kk = 0; kk < KB; kk += 32) {
            bf16x8 a0 = *(const bf16x8*)&T[wrow + lr][kk + quad * 8];
            bf16x8 b0 = *(const bf16x8*)&Ws[wn + lr     ][kk + quad * 8];
            bf16x8 b1 = *(const bf16x8*)&Ws[wn + 16 + lr][kk + quad * 8];
            acc2[0] = __builtin_amdgcn_mfma_f32_16x16x32_bf16(a0, b0, acc2[0], 0, 0, 0);
            acc2[1] = __builtin_amdgcn_mfma_f32_16x16x32_bf16(a0, b1, acc2[1], 0, 0, 0);
        }
        if (piece == 0) {
            #pragma unroll
            for (int j = 0; j < 2; j++) {
                int gn = c0 + wn + j * 16 + lr;
                float bb = b2[gn];
                #pragma unroll
                for (int rr = 0; rr < 4; rr++)
                    avvr[j][rr] = acc2[j][rr] + bb;
            }
        } else if (piece == 1) {
            #pragma unroll
            for (int j = 0; j < 2; j++) {
                int gn = c0 + wn + j * 16 + lr;
                float bb = b2[gn];
                #pragma unroll
                for (int rr = 0; rr < 4; rr++)
                    asvr[j][rr] = acc2[j][rr] + bb;
            }
        } else {
            // ass chunk: full node update + As s-deposit
            #pragma unroll
            for (int j = 0; j < 2; j++) {
                int gn = c0 + wn + j * 16 + lr;
                int f  = gn - 256;          // = part*64 + wn + j*16 + lr
                float bb = b2[gn];
                #pragma unroll
                for (int rr = 0; rr < 4; rr++) {
                    int row = wrow + quad * 4 + rr;
                    int gm = bm + row;
                    if (gm < M) {
                        float ass = acc2[j][rr] + bb;
                        float asv = asvr[j][rr];
                        float avv = avvr[j][rr];
                        int vb = gm * F3 + f;
                        float u0 = b2f(Uv[vb]);
                        float u1 = b2f(Uv[vb + FD]);
                        float u2 = b2f(Uv[vb + 2 * FD]);
                        float w0 = b2f(Vv[vb]);
                        float w1 = b2f(Vv[vb + FD]);
                        float w2 = b2f(Vv[vb + 2 * FD]);
                        float dot = u0 * w0 + u1 * w1 + u2 * w2;
                        int nb = gm * FD + f;
                        float so = s_mid[nb] + ass + asv * dot;
                        s_out[nb] = so;
                        As[row][f] = f2b(so);
                        float y0 = v_mid[vb]          + avv * u0;
                        float y1 = v_mid[vb + FD]     + avv * u1;
                        float y2 = v_mid[vb + 2 * FD] + avv * u2;
                        v_out[vb]          = y0;
                        v_out[vb + FD]     = y1;
                        v_out[vb + 2 * FD] = y2;
                        char* vpb = (char*)v_pk + (size_t)gm * (2 * F3);
                        *(u32*)(vpb + 4 * f) = pack2(y0, y1);
                        *(u16*)(vpb + 512 + 2 * f) = f2b(y2);
                    } else {
                        As[row][f] = 0;
                    }
                }
            }
        }
        __syncthreads();   // piece consumed (and As deposit visible) before restage
    }
    // As now holds this block's fresh s (bf16), 32 rows x 128 cols.

    if constexpr (!LAST) {
        // ---------------- appended mlp1 of next iteration (A = As, K=128)
        {
            #pragma unroll
            for (int h = 0; h < 2; h++) {
                int wr = r + h * 64;
                const u16* wp = N_W1 + (size_t)wr * KB + q * 32;
                u16* dW = &Ws[wr][q * 32];
                #pragma unroll
                for (int x = 0; x < 32; x += 8)
                    *(bf16x8*)&dW[x] = *(const bf16x8*)(wp + x);
            }
        }
        __syncthreads();
        #pragma unroll
        for (int j = 0; j < 4; j++) acc1[j] = (floatx4)0.f;
        #pragma unroll
        for (int kk = 0; kk < KB; kk += 32) {
            bf16x8 a0 = *(const bf16x8*)&As[wrow + lr][kk + quad * 8];
            #pragma unroll
            for (int j = 0; j < 4; j++) {
                bf16x8 b = *(const bf16x8*)&Ws[wn1 + j * 16 + lr][kk + quad * 8];
                acc1[j] = __builtin_amdgcn_mfma_f32_16x16x32_bf16(a0, b, acc1[j], 0, 0, 0);
            }
        }
        __syncthreads();   // Ws consumed -> T region writable
        #pragma unroll
        for (int j = 0; j < 4; j++) {
            int col = wn1 + j * 16 + lr;
            float bb = N_b1[col];
            #pragma unroll
            for (int rr = 0; rr < 4; rr++) {
                int row = wrow + quad * 4 + rr;
                float v = acc1[j][rr] + bb;
                v = v / (1.f + __expf(-v));
                T[row][col] = f2b(v);
            }
        }
        // GEMM2 (6 pieces of 64 cols into Ws[0..63])
        for (int pp = 0; pp < 6; pp++) {
            const int c0 = pp * 64;
            {
                const u16* wp = N_W2 + (size_t)(c0 + r) * KB + q * 32;
                u16* dW = &Ws[r][q * 32];
                #pragma unroll
                for (int x = 0; x < 32; x += 8)
                    *(bf16x8*)&dW[x] = *(const bf16x8*)(wp + x);
            }
            __syncthreads();   // (pp==0: also covers T-write)
            floatx4 acc2[2];
            #pragma unroll
            for (int j = 0; j < 2; j++) acc2[j] = (floatx4)0.f;
            #pragma unroll
            for (int kk = 0; kk < KB; kk += 32) {
                bf16x8 a0 = *(const bf16x8*)&T[wrow + lr][kk + quad * 8];
                bf16x8 b0 = *(const bf16x8*)&Ws[wn + lr     ][kk + quad * 8];
                bf16x8 b1 = *(const bf16x8*)&Ws[wn + 16 + lr][kk + quad * 8];
                acc2[0] = __builtin_amdgcn_mfma_f32_16x16x32_bf16(a0, b0, acc2[0], 0, 0, 0);
                acc2[1] = __builtin_amdgcn_mfma_f32_16x16x32_bf16(a0, b1, acc2[1], 0, 0, 0);
            }
            #pragma unroll
            for (int j = 0; j < 2; j++) {
                int gn = c0 + wn + j * 16 + lr;
                float bb = N_b2[gn];
                #pragma unroll
                for (int rr = 0; rr < 4; rr++) {
                    int gm = bm + wrow + quad * 4 + rr;
                    if (gm < M) {
                        u16 val = f2b(acc2[j][rr] + bb);
                        int off = (gn < 256) ? ((gn & 127) * 2 + (gn >> 7))
                                             : (256 + (gn & 127));
                        a_pk[(size_t)gm * F3 + off] = val;
                    }
                }
            }
            __syncthreads();
        }
    } else {
        // ---------------- appended final head: t = silu(s@ow1^T+ob1); nodeval = t·ow2 + ob2
        {
            #pragma unroll
            for (int h = 0; h < 2; h++) {
                int wr = r + h * 64;
                const u16* wp = H_W1 + (size_t)wr * KB + q * 32;
                u16* dW = &Ws[wr][q * 32];
                #pragma unroll
                for (int x = 0; x < 32; x += 8)
                    *(bf16x8*)&dW[x] = *(const bf16x8*)(wp + x);
            }
        }
        __syncthreads();
        #pragma unroll
        for (int j = 0; j < 4; j++) acc1[j] = (floatx4)0.f;
        #pragma unroll
        for (int kk = 0; kk < KB; kk += 32) {
            bf16x8 a0 = *(const bf16x8*)&As[wrow + lr][kk + quad * 8];
            #pragma unroll
            for (int j = 0; j < 4; j++) {
                bf16x8 b = *(const bf16x8*)&Ws[wn1 + j * 16 + lr][kk + quad * 8];
                acc1[j] = __builtin_amdgcn_mfma_f32_16x16x32_bf16(a0, b, acc1[j], 0, 0, 0);
            }
        }
        __syncthreads();   // Ws + As fully consumed
        float* ow2s = (float*)&As[0][0];   // 128 f32 (As dead)
        if (tid < KB) ow2s[tid] = ow2[tid];
        #pragma unroll
        for (int j = 0; j < 4; j++) {
            int col = wn1 + j * 16 + lr;
            float bb = H_b1[col];
            #pragma unroll
            for (int rr = 0; rr < 4; rr++) {
                int row = wrow + quad * 4 + rr;
                float v = acc1[j][rr] + bb;
                v = v / (1.f + __expf(-v));
                T[row][col] = f2b(v);      // bf16 t in Ws[64..]
            }
        }
        __syncthreads();
        // dot with ow2: 8 threads per node, 16 cols each, shfl-reduce within 8-lane group
        int nl = tid >> 3, seg = tid & 7;
        float v = 0.f;
        #pragma unroll
        for (int x = 0; x < 16; x++) {
            int col = seg * 16 + x;
            v += b2f(T[nl][col]) * ow2s[col];
        }
        v += __shfl_down(v, 4);
        v += __shfl_down(v, 2);
        v += __shfl_down(v, 1);
        if (seg == 0) {
            int gm = bm + nl;
            if (gm < M) nodeval[gm] = v + ob2[0];
        }
    }
}

__global__ __launch_bounds__(1024) void mol_reduce_kernel(const float* __restrict__ nodeval,
    const int* __restrict__ gidx, float* __restrict__ out)
{
    __shared__ float mol[NMOL];
    int tid = threadIdx.x;
    if (tid < NMOL) mol[tid] = 0.f;
    __syncthreads();
    int cur = -1; float acc = 0.f;
    for (int x = tid; x < NN; x += 1024) {
        int g = gidx[x];
        float v = nodeval[x];
        if (g != cur) {
            if (cur >= 0) atomicAdd(&mol[cur], acc);
            cur = g; acc = v;
        } else acc += v;
    }
    if (cur >= 0) atomicAdd(&mol[cur], acc);
    __syncthreads();
    if (tid < NMOL) out[tid] = mol[tid];
}

// ---------------------------------------------------------------- launch
extern "C" void kernel_launch(void* const* d_in, const int* in_sizes, int n_in,
                              void* d_out, int out_size, void* d_ws, size_t ws_size,
                              hipStream_t stream)
{
    const int*   z     = (const int*)d_in[0];
    const int*   graph = (const int*)d_in[1];
    const float* dist  = (const float*)d_in[2];
    const float* sense = (const float*)d_in[3];
    const int*   gidx  = (const int*)d_in[4];
    const float* emb   = (const float*)d_in[5];
    const float* mw1   = (const float*)d_in[6];
    const float* mb1   = (const float*)d_in[7];
    const float* mw2   = (const float*)d_in[8];
    const float* mb2   = (const float*)d_in[9];
    const float* ew    = (const float*)d_in[10];
    const float* eb    = (const float*)d_in[11];
    const float* uw    = (const float*)d_in[12];
    const float* vw    = (const float*)d_in[13];
    const float* aw1   = (const float*)d_in[14];
    const float* ab1   = (const float*)d_in[15];
    const float* aw2   = (const float*)d_in[16];
    const float* ab2   = (const float*)d_in[17];
    const float* ow1   = (const float*)d_in[18];
    const float* ob1   = (const float*)d_in[19];
    const float* ow2   = (const float*)d_in[20];
    const float* ob2   = (const float*)d_in[21];
    float* out = (float*)d_out;

    // ---- workspace carve-up ----
    float* W = (float*)d_ws;
    float* s_a    = W; W += (size_t)NN * FD;
    float* s_b    = W; W += (size_t)NN * FD;
    float* v_a    = W; W += (size_t)NN * F3;
    float* v_b    = W; W += (size_t)NN * F3;
    float* cut_p  = W; W += (size_t)NE;
    float* sns_p  = W; W += (size_t)NE * 3;
    float* nodeval= W; W += (size_t)NN;
    u16* U = (u16*)W;
    u16* sbf_a = U; U += (size_t)NN * FD;
    u16* sbf_b = U; U += (size_t)NN * FD;
    u16* vbf_b = U; U += (size_t)NN * F3;
    u16* a_pk  = U; U += (size_t)NN * F3;
    u16* v_pk  = U; U += (size_t)NN * F3;
    u16* h_bf  = U; U += (size_t)NN * F2;   // unused (layout stability)
    u16* a2_bf = U; U += (size_t)NN * F3;   // unused (layout stability)
    u16* Uv_bf = U; U += (size_t)NN * F3;
    u16* Vv_bf = U; U += (size_t)NN * F3;
    u16* rbf_bf= U; U += (size_t)NE * 32;
    u16* ewb   = U; U += (size_t)NITER * F3 * 32;
    u16* wb    = U; U += 557056;
    int* ip = (int*)U;
    int* row_ptr   = ip; ip += NN + 1;
    int* cnt       = ip; ip += NN;
    int* cursor    = ip; ip += NN;
    int* edge_list = ip; ip += NE;
    int* dst_p     = ip; ip += NE;

    // bf16 weight table offsets
    u16* wb_mw1 = wb;            // 3*128*128
    u16* wb_mw2 = wb + 49152;    // 3*384*128
    u16* wb_uw  = wb + 196608;   // 3*128*128
    u16* wb_vw  = wb + 245760;   // 3*128*128
    u16* wb_aw1 = wb + 294912;   // 3*128*256
    u16* wb_aw2 = wb + 393216;   // 3*384*128
    u16* wb_ow1 = wb + 540672;   // 128*128

    const int TB = 256;
    dim3 b256(TB);

    // --- precompute ---
    init_all_kernel<<<dim3((NN * F3 + TB - 1) / TB), b256, 0, stream>>>(
        mw1, 49152, mw2, 147456, uw, 49152, vw, 49152, aw1, 98304, aw2, 147456,
        ow1, 16384, wb, ew, ewb, z, emb, s_a, sbf_a, v_a, (int*)v_pk, cnt);
    csr_count_kernel<<<dim3((NE + TB - 1) / TB), b256, 0, stream>>>(graph, cnt);
    csr_scan_kernel<<<dim3(1), dim3(1024), 0, stream>>>(cnt, row_ptr, cursor);
    csr_scatter_kernel<<<dim3((NE + TB - 1) / TB), b256, 0, stream>>>(graph, cursor, edge_list);
    edge_stream_kernel<<<dim3((NE + TB - 1) / TB), b256, 0, stream>>>(
        edge_list, graph, dist, sense, rbf_bf, cut_p, sns_p, dst_p);

    dim3 gM2((NN + BM2 - 1) / BM2);             // node kernels (BM=32, 625 blocks)
    dim3 gUV((3 * NN + BM2 - 1) / BM2);         // gemm_uv (BM=32, 1875 blocks)

    // iter-0 message MLP (later iterations' mlp1 are fused into mlp2_update_next)
    mlp1_kernel<<<gM2, b256, 0, stream>>>(sbf_a,
        wb_mw1, mb1, wb_mw2, mb2, a_pk, NN);

    for (int i = 0; i < NITER; i++) {
        edge_mfma_kernel<<<dim3(NN), b256, 0, stream>>>(
            rbf_bf, cut_p, sns_p, dst_p,
            ewb + (size_t)i * F3 * 32, eb + (size_t)i * F3,
            a_pk, s_a, v_a, v_pk, row_ptr, s_b, sbf_b, v_b, vbf_b);
        gemm_uv<<<gUV, b256, 0, stream>>>(vbf_b, wb_uw + (size_t)i * FD * FD,
            wb_vw + (size_t)i * FD * FD, Uv_bf, Vv_bf, 3 * NN);
        if (i < NITER - 1) {
            mlp2_update_next_kernel<false><<<gM2, b256, 0, stream>>>(
                sbf_b, s_b, v_b, Uv_bf, Vv_bf,
                wb_aw1 + (size_t)i * FD * F2, ab1 + (size_t)i * FD,
                wb_aw2 + (size_t)i * F3 * FD, ab2 + (size_t)i * F3,
                s_a, v_a, v_pk,
                wb_mw1 + (size_t)(i + 1) * FD * FD, mb1 + (size_t)(i + 1) * FD,
                wb_mw2 + (size_t)(i + 1) * F3 * FD, mb2 + (size_t)(i + 1) * F3, a_pk,
                nullptr, nullptr, nullptr, nullptr, nullptr, NN);
        } else {
            mlp2_update_next_kernel<true><<<gM2, b256, 0, stream>>>(
                sbf_b, s_b, v_b, Uv_bf, Vv_bf,
                wb_aw1 + (size_t)i * FD * F2, ab1 + (size_t)i * FD,
                wb_aw2 + (size_t)i * F3 * FD, ab2 + (size_t)i * F3,
                s_a, v_a, v_pk,
                nullptr, nullptr, nullptr, nullptr, nullptr,
                wb_ow1, ob1, ow2, ob2, nodeval, NN);
        }
    }

    mol_reduce_kernel<<<dim3(1), dim3(1024), 0, stream>>>(nodeval, gidx, out);
}

// Round 12
// 810.822 us; speedup vs baseline: 1.1526x; 1.0491x over previous
//
#include <hip/hip_runtime.h>
#include <math.h>

// Problem constants
#define NN 20000
#define NE 320000
#define FD 128
#define RBFN 20
#define RC_ 5.0f
#define NITER 3
#define NMOL 64
#define F3 384
#define F2 256
#define PI_ 3.14159265358979323846f
#define KB 128
#define LPAD 8
#define SDS2 200  // u16 stride per sdrep edge row in f-split edge kernel (192 + 8 pad)
#define BM2 32    // node-path rows/block (more blocks/CU — validated lever, r9)

typedef __attribute__((ext_vector_type(8))) short  bf16x8;
typedef __attribute__((ext_vector_type(4))) float  floatx4;
typedef unsigned short u16;
typedef unsigned int   u32;

__device__ __forceinline__ u16 f2b(float x) {
    union { float f; unsigned int u; } v; v.f = x;
    unsigned int u = v.u;
    return (u16)((u + 0x7fffu + ((u >> 16) & 1u)) >> 16);   // RNE
}
__device__ __forceinline__ float b2f(u16 x) {
    union { unsigned int u; float f; } v; v.u = ((unsigned int)x) << 16;
    return v.f;
}
__device__ __forceinline__ float blo(u32 w) {
    union { unsigned int u; float f; } v; v.u = w << 16; return v.f;
}
__device__ __forceinline__ float bhi(u32 w) {
    union { unsigned int u; float f; } v; v.u = w & 0xffff0000u; return v.f;
}
__device__ __forceinline__ u32 pack2(float a, float b) {
    return (u32)f2b(a) | ((u32)f2b(b) << 16);
}

// ---------------------------------------------------------------- fused one-time init
__global__ __launch_bounds__(256) void init_all_kernel(
    const float* s0, int n0, const float* s1, int n1, const float* s2, int n2,
    const float* s3, int n3, const float* s4, int n4, const float* s5, int n5,
    const float* s6, int n6, u16* __restrict__ wdst,
    const float* __restrict__ ew, u16* __restrict__ ewb,
    const int* __restrict__ z, const float* __restrict__ emb,
    float* __restrict__ s, u16* __restrict__ sbf,
    float* __restrict__ v_a, int* __restrict__ v_pk_i, int* __restrict__ cnt,
    float* __restrict__ out)
{
    int idx = blockIdx.x * 256 + threadIdx.x;
    if (idx < NN * F3) v_a[idx] = 0.f;
    if (idx < NN * F3 / 2) v_pk_i[idx] = 0;
    if (idx < NN) cnt[idx] = 0;
    if (idx < NMOL) out[idx] = 0.f;
    if (idx < NN * FD) {
        int n = idx >> 7, f = idx & 127;
        float v = emb[z[n] * FD + f];
        s[idx] = v; sbf[idx] = f2b(v);
    }
    if (idx < NITER * F3 * 32) {
        int k = idx & 31;
        int row = idx >> 5;
        ewb[idx] = (k < RBFN) ? f2b(ew[row * RBFN + k]) : (u16)0;
    }
    {
        int w = idx;
        u16* dst = wdst;
        if (w < n0) { dst[w] = f2b(s0[w]); return; } w -= n0; dst += n0;
        if (w < n1) { dst[w] = f2b(s1[w]); return; } w -= n1; dst += n1;
        if (w < n2) { dst[w] = f2b(s2[w]); return; } w -= n2; dst += n2;
        if (w < n3) { dst[w] = f2b(s3[w]); return; } w -= n3; dst += n3;
        if (w < n4) { dst[w] = f2b(s4[w]); return; } w -= n4; dst += n4;
        if (w < n5) { dst[w] = f2b(s5[w]); return; } w -= n5; dst += n5;
        if (w < n6) { dst[w] = f2b(s6[w]); }
    }
}

// ---------------------------------------------------------------- CSR build
__global__ __launch_bounds__(256) void csr_count_kernel(const int* __restrict__ graph,
    int* __restrict__ cnt)
{
    int e = blockIdx.x * 256 + threadIdx.x;
    if (e >= NE) return;
    atomicAdd(&cnt[graph[2 * e]], 1);
}

__global__ __launch_bounds__(1024) void csr_scan_kernel(const int* __restrict__ cnt,
    int* __restrict__ row_ptr, int* __restrict__ cursor)
{
    __shared__ int sd[1024];
    int tid = threadIdx.x;
    const int chunk = (NN + 1023) / 1024;
    int start = tid * chunk;
    int end = start + chunk; if (end > NN) end = NN;
    int sum = 0;
    for (int j = start; j < end; j++) sum += cnt[j];
    sd[tid] = sum;
    __syncthreads();
    for (int off = 1; off < 1024; off <<= 1) {
        int v = 0;
        if (tid >= off) v = sd[tid - off];
        __syncthreads();
        if (tid >= off) sd[tid] += v;
        __syncthreads();
    }
    int run = (tid == 0) ? 0 : sd[tid - 1];
    for (int j = start; j < end; j++) {
        row_ptr[j] = run;
        cursor[j]  = run;
        run += cnt[j];
    }
    if (tid == 0) row_ptr[NN] = NE;
}

__global__ __launch_bounds__(256) void csr_scatter_kernel(const int* __restrict__ graph,
    int* __restrict__ cursor, int* __restrict__ edge_list)
{
    int e = blockIdx.x * 256 + threadIdx.x;
    if (e >= NE) return;
    int p = atomicAdd(&cursor[graph[2 * e]], 1);
    edge_list[p] = e;
}

// Permuted edge streams in CSR order; Chebyshev sin recurrence; vectorized rbf stores.
__global__ __launch_bounds__(256) void edge_stream_kernel(
    const int* __restrict__ edge_list, const int* __restrict__ graph,
    const float* __restrict__ dist, const float* __restrict__ sense,
    u16* __restrict__ rbf_bf, float* __restrict__ cut_p,
    float* __restrict__ sense_p, int* __restrict__ dst_p)
{
    int j = blockIdx.x * 256 + threadIdx.x;
    if (j >= NE) return;
    int e = edge_list[j];
    float d = dist[e];
    float inv = 1.f / d;
    float base = PI_ * d / RC_;
    float s1, c1;
    __sincosf(base, &s1, &c1);
    float twoc = c1 + c1;
    u16 tmp[32];
    float sprev = 0.f, scur = s1;
    #pragma unroll
    for (int k = 0; k < RBFN; k++) {
        tmp[k] = f2b(scur * inv);
        float snext = twoc * scur - sprev;
        sprev = scur; scur = snext;
    }
    #pragma unroll
    for (int k = RBFN; k < 32; k++) tmp[k] = 0;
    u16* rb = rbf_bf + (size_t)j * 32;
    #pragma unroll
    for (int x = 0; x < 32; x += 8)
        *(bf16x8*)&rb[x] = *(const bf16x8*)&tmp[x];
    cut_p[j] = 0.5f * (c1 + 1.f) * (d < RC_ ? 1.f : 0.f);
    dst_p[j] = graph[2 * e + 1];
    sense_p[3 * j + 0] = sense[3 * e + 0];
    sense_p[3 * j + 1] = sense[3 * e + 1];
    sense_p[3 * j + 2] = sense[3 * e + 2];
}

// ---------------------------------------------------------------- iter-0 message MLP (BM=32)
__global__ __launch_bounds__(256) void mlp1_kernel(const u16* __restrict__ A,
    const u16* __restrict__ W1, const float* __restrict__ b1,
    const u16* __restrict__ W2, const float* __restrict__ b2,
    u16* __restrict__ Ob, int M)
{
    __shared__ u16 As[BM2][KB + LPAD];
    __shared__ u16 Ws[128][KB + LPAD];
    u16 (*T)[KB + LPAD] = &Ws[64];     // alias: valid only after GEMM1 consumed Ws
    const int bm = blockIdx.x * BM2;
    const int tid = threadIdx.x;
    const int wave = tid >> 6, lane = tid & 63;
    const int wrow = (wave >> 1) * 16;
    const int wn1  = (wave & 1) * 64;
    const int wn   = (wave & 1) * 32;
    const int quad = lane >> 4, lr = lane & 15;
    const int r = tid >> 2, q = tid & 3;
    const int r3 = tid >> 3, c16 = (tid & 7) * 16;

    floatx4 acc1[4];
    #pragma unroll
    for (int j = 0; j < 4; j++) acc1[j] = (floatx4)0.f;

    {
        int gm = bm + r3;
        u16* dA = &As[r3][c16];
        if (gm < M) {
            const u16* ap = A + (size_t)gm * KB + c16;
            *(bf16x8*)&dA[0] = *(const bf16x8*)(ap);
            *(bf16x8*)&dA[8] = *(const bf16x8*)(ap + 8);
        } else {
            *(bf16x8*)&dA[0] = (bf16x8)0;
            *(bf16x8*)&dA[8] = (bf16x8)0;
        }
        #pragma unroll
        for (int h = 0; h < 2; h++) {
            int wr = r + h * 64;
            const u16* wp = W1 + (size_t)wr * KB + q * 32;
            u16* dW = &Ws[wr][q * 32];
            #pragma unroll
            for (int x = 0; x < 32; x += 8)
                *(bf16x8*)&dW[x] = *(const bf16x8*)(wp + x);
        }
    }
    __syncthreads();
    #pragma unroll
    for (int kk = 0; kk < KB; kk += 32) {
        bf16x8 a0 = *(const bf16x8*)&As[wrow + lr][kk + quad * 8];
        #pragma unroll
        for (int j = 0; j < 4; j++) {
            bf16x8 b = *(const bf16x8*)&Ws[wn1 + j * 16 + lr][kk + quad * 8];
            acc1[j] = __builtin_amdgcn_mfma_f32_16x16x32_bf16(a0, b, acc1[j], 0, 0, 0);
        }
    }
    __syncthreads();   // Ws consumed -> T region writable
    #pragma unroll
    for (int j = 0; j < 4; j++) {
        int col = wn1 + j * 16 + lr;
        float bb = b1[col];
        #pragma unroll
        for (int rr = 0; rr < 4; rr++) {
            int row = wrow + quad * 4 + rr;
            float v = acc1[j][rr] + bb;
            v = v / (1.f + __expf(-v));
            T[row][col] = f2b(v);
        }
    }
    for (int pp = 0; pp < 6; pp++) {
        const int c0 = pp * 64;
        {
            const u16* wp = W2 + (size_t)(c0 + r) * KB + q * 32;
            u16* dW = &Ws[r][q * 32];
            #pragma unroll
            for (int x = 0; x < 32; x += 8)
                *(bf16x8*)&dW[x] = *(const bf16x8*)(wp + x);
        }
        __syncthreads();   // (pp==0: also covers T-write)
        floatx4 acc2[2];
        #pragma unroll
        for (int j = 0; j < 2; j++) acc2[j] = (floatx4)0.f;
        #pragma unroll
        for (int kk = 0; kk < KB; kk += 32) {
            bf16x8 a0 = *(const bf16x8*)&T[wrow + lr][kk + quad * 8];
            bf16x8 b0 = *(const bf16x8*)&Ws[wn + lr     ][kk + quad * 8];
            bf16x8 b1 = *(const bf16x8*)&Ws[wn + 16 + lr][kk + quad * 8];
            acc2[0] = __builtin_amdgcn_mfma_f32_16x16x32_bf16(a0, b0, acc2[0], 0, 0, 0);
            acc2[1] = __builtin_amdgcn_mfma_f32_16x16x32_bf16(a0, b1, acc2[1], 0, 0, 0);
        }
        #pragma unroll
        for (int j = 0; j < 2; j++) {
            int gn = c0 + wn + j * 16 + lr;
            float bb = b2[gn];
            #pragma unroll
            for (int rr = 0; rr < 4; rr++) {
                int gm = bm + wrow + quad * 4 + rr;
                if (gm < M) {
                    u16 val = f2b(acc2[j][rr] + bb);
                    int off = (gn < 256) ? ((gn & 127) * 2 + (gn >> 7))
                                         : (256 + (gn & 127));
                    Ob[(size_t)gm * F3 + off] = val;
                }
            }
        }
        __syncthreads();
    }
}

// Dual GEMM: U = A@Wu^T, V = A@Wv^T (K=128, Nc=128). bf16 outs. BM=32 re-tile (1875 blocks).
__global__ __launch_bounds__(256) void gemm_uv(const u16* __restrict__ A,
    const u16* __restrict__ Wu, const u16* __restrict__ Wv,
    u16* __restrict__ U, u16* __restrict__ V, int M)
{
    __shared__ u16 As[BM2][KB + LPAD];
    __shared__ u16 Bu[64][KB + LPAD];
    __shared__ u16 Bv[64][KB + LPAD];
    const int bm = blockIdx.x * BM2;
    const int tid = threadIdx.x;
    const int r = tid >> 2;
    const int q = tid & 3;
    const int r3 = tid >> 3, c16 = (tid & 7) * 16;
    const int wave = tid >> 6;
    const int lane = tid & 63;
    const int wrow = (wave >> 1) * 16;
    const int wn = (wave & 1) * 32;
    const int quad = lane >> 4;
    const int lr = lane & 15;

    {
        int gm = bm + r3;
        u16* dA = &As[r3][c16];
        if (gm < M) {
            const u16* ap = A + (size_t)gm * KB + c16;
            *(bf16x8*)&dA[0] = *(const bf16x8*)(ap);
            *(bf16x8*)&dA[8] = *(const bf16x8*)(ap + 8);
        } else {
            *(bf16x8*)&dA[0] = (bf16x8)0;
            *(bf16x8*)&dA[8] = (bf16x8)0;
        }
    }

    #pragma unroll
    for (int bn = 0; bn < FD; bn += 64) {
        {
            int gn = bn + r;
            const u16* up = Wu + (size_t)gn * KB + q * 32;
            const u16* vp = Wv + (size_t)gn * KB + q * 32;
            u16* dU = &Bu[r][q * 32];
            u16* dV = &Bv[r][q * 32];
            #pragma unroll
            for (int x = 0; x < 32; x += 8) {
                *(bf16x8*)&dU[x] = *(const bf16x8*)(up + x);
                *(bf16x8*)&dV[x] = *(const bf16x8*)(vp + x);
            }
        }
        __syncthreads();
        floatx4 au[2], av[2];
        #pragma unroll
        for (int j = 0; j < 2; j++) { au[j] = (floatx4)0.f; av[j] = (floatx4)0.f; }
        #pragma unroll
        for (int kk = 0; kk < KB; kk += 32) {
            bf16x8 a0 = *(const bf16x8*)&As[wrow + lr][kk + quad * 8];
            bf16x8 u0 = *(const bf16x8*)&Bu[wn + lr     ][kk + quad * 8];
            bf16x8 u1 = *(const bf16x8*)&Bu[wn + 16 + lr][kk + quad * 8];
            bf16x8 v0 = *(const bf16x8*)&Bv[wn + lr     ][kk + quad * 8];
            bf16x8 v1 = *(const bf16x8*)&Bv[wn + 16 + lr][kk + quad * 8];
            au[0] = __builtin_amdgcn_mfma_f32_16x16x32_bf16(a0, u0, au[0], 0, 0, 0);
            au[1] = __builtin_amdgcn_mfma_f32_16x16x32_bf16(a0, u1, au[1], 0, 0, 0);
            av[0] = __builtin_amdgcn_mfma_f32_16x16x32_bf16(a0, v0, av[0], 0, 0, 0);
            av[1] = __builtin_amdgcn_mfma_f32_16x16x32_bf16(a0, v1, av[1], 0, 0, 0);
        }
        #pragma unroll
        for (int j = 0; j < 2; j++) {
            int gn = bn + wn + j * 16 + lr;
            #pragma unroll
            for (int rr = 0; rr < 4; rr++) {
                int gm = bm + wrow + quad * 4 + rr;
                if (gm < M) {
                    U[(size_t)gm * FD + gn] = f2b(au[j][rr]);
                    V[(size_t)gm * FD + gn] = f2b(av[j][rr]);
                }
            }
        }
        __syncthreads();   // Bu/Bv fully consumed before restage
    }
}

// ---------------------------------------------------------------- edge aggregate (MFMA dist_rep)
// F-SPLIT form (r12): grid (NN, 2) x 128 threads — each block handles one node's f-half.
// Per-(n,f) arithmetic byte-identical to the proven 256-thread form; block granularity
// halved to raise achieved blocks/CU (the r9-validated lever, untried on edge until now).
__global__ __launch_bounds__(128) void edge_mfma_kernel(
    const u16* __restrict__ rbf_bf, const float* __restrict__ cut_p,
    const float* __restrict__ sense_p, const int* __restrict__ dst_p,
    const u16* __restrict__ ewb, const float* __restrict__ eb,
    const u16* __restrict__ a_pk, const float* __restrict__ s_in,
    const float* __restrict__ v_in, const u16* __restrict__ v_pk,
    const int* __restrict__ row_ptr,
    float* __restrict__ s_out, u16* __restrict__ s_obf,
    float* __restrict__ v_out, u16* __restrict__ v_obf)
{
    __shared__ u16   sdrep[16 * SDS2];   // planar bf16: [e][192 local cols] — 6.25 KB
    __shared__ float scut[16];
    __shared__ float ssen[16][4];
    __shared__ int   sdst[16];
    __shared__ float red[4 * 64];

    const int n = blockIdx.x;
    const int h = blockIdx.y;           // f-half: covers f in [h*64, h*64+64)
    const int tid = threadIdx.x;        // 0..127
    const int wave = tid >> 6;          // 0..1
    const int lane = tid & 63;
    const int quad = lane >> 4;
    const int lr = lane & 15;
    const int fl = tid & 63;            // local f
    const int fg = h * 64 + fl;         // global f
    const int grp = tid >> 6;           // edge half (8 edges each)

    int beg = row_ptr[n], end = row_ptr[n + 1];
    float accs = 0.f, accv0 = 0.f, accv1 = 0.f, accv2 = 0.f;

    for (int t0 = beg; t0 < end; t0 += 16) {
        int cnt = end - t0; if (cnt > 16) cnt = 16;
        __syncthreads();   // previous tile fully consumed
        if (tid < 16) {
            scut[tid] = (tid < cnt) ? cut_p[t0 + tid] : 0.f;
            sdst[tid] = (tid < cnt) ? dst_p[t0 + tid] : 0;
        }
        if (tid >= 64 && tid < 64 + 3 * cnt) {
            int x = tid - 64;
            ssen[x / 3][x % 3] = sense_p[3 * t0 + x];
        }
        // MFMA: A = rbf rows (lane m=lr = edge), B = ew rows; this block covers the
        // 3x64 output cols {comp*128 + h*64 .. +63} as 12 col-tiles (6 per wave).
        bf16x8 afrag;
        int ge = t0 + lr;
        if (ge < end) afrag = *(const bf16x8*)&rbf_bf[(size_t)ge * 32 + quad * 8];
        else          afrag = (bf16x8)0;
        floatx4 dacc[6];
        #pragma unroll
        for (int nt = 0; nt < 6; nt++) {
            int tt = wave * 6 + nt;
            int comp = tt >> 2, sub = tt & 3;
            int nrow = comp * 128 + h * 64 + sub * 16 + lr;
            bf16x8 bfrag = *(const bf16x8*)&ewb[(size_t)nrow * 32 + quad * 8];
            dacc[nt] = __builtin_amdgcn_mfma_f32_16x16x32_bf16(afrag, bfrag, (floatx4)0.f, 0, 0, 0);
        }
        __syncthreads();   // staged scalars visible
        // epilogue: (d + eb) * cut -> planar bf16 sdrep (local col = comp*64 + sub*16 + lr)
        #pragma unroll
        for (int nt = 0; nt < 6; nt++) {
            int tt = wave * 6 + nt;
            int comp = tt >> 2, sub = tt & 3;
            int ncg = comp * 128 + h * 64 + sub * 16 + lr;
            int lc  = comp * 64 + sub * 16 + lr;
            float ebn = eb[ncg];
            #pragma unroll
            for (int rr = 0; rr < 4; rr++) {
                int e = quad * 4 + rr;
                sdrep[e * SDS2 + lc] = f2b((dacc[nt][rr] + ebn) * scut[e]);
            }
        }
        __syncthreads();   // sdrep ready
        // aggregation: group handles up to 8 edges (proven serial runtime-bound form)
        int nh = cnt - grp * 8; if (nh > 8) nh = 8;
        for (int k = 0; k < nh; k++) {
            int e = grp * 8 + k;
            int dst = sdst[e];
            const u16* sr = &sdrep[e * SDS2];
            float drv = b2f(sr[fl]);
            float drs = b2f(sr[64 + fl]);
            float drd = b2f(sr[128 + fl]);
            const u16* ar = a_pk + (size_t)dst * F3;
            u32 ap = *(const u32*)(ar + fg * 2);
            float rv = b2f((u16)(ap & 0xffff)) * drv;
            float rs = b2f((u16)(ap >> 16))    * drs;
            float rd = b2f(ar[256 + fg])       * drd;
            accs += rs;
            const u16* vr = v_pk + (size_t)dst * F3;
            u32 vp = *(const u32*)(vr + fg * 2);
            accv0 += b2f((u16)(vp & 0xffff)) * rv + ssen[e][0] * rd;
            accv1 += b2f((u16)(vp >> 16))    * rv + ssen[e][1] * rd;
            accv2 += b2f(vr[256 + fg])       * rv + ssen[e][2] * rd;
        }
    }
    // combine the two edge-groups, write this f-half
    __syncthreads();
    if (grp == 1) {
        red[fl] = accs; red[64 + fl] = accv0; red[128 + fl] = accv1; red[192 + fl] = accv2;
    }
    __syncthreads();
    if (grp == 0) {
        accs  += red[fl];       accv0 += red[64 + fl];
        accv1 += red[128 + fl]; accv2 += red[192 + fl];
        int nb = n * FD + fg;
        float so = s_in[nb] + 2.f * accs;
        s_out[nb] = so; s_obf[nb] = f2b(so);
        int vb = n * F3 + fg;
        float w0 = v_in[vb]           + 2.f * accv0;
        float w1 = v_in[vb + FD]      + 2.f * accv1;
        float w2 = v_in[vb + 2 * FD]  + 2.f * accv2;
        v_out[vb]          = w0; v_obf[vb]          = f2b(w0);
        v_out[vb + FD]     = w1; v_obf[vb + FD]     = f2b(w1);
        v_out[vb + 2 * FD] = w2; v_obf[vb + 2 * FD] = f2b(w2);
    }
}

// ---------------------------------------------------------------- fused mlp2 + build_h + update + NEXT
// BM=32 (625 blocks). T aliased onto Ws[64..127]; ass chunk does node update inline and
// deposits fresh s into As.  LAST=false appends next mlp1; LAST=true appends head writing
// nodeval (plain stores — atomicAdd-to-64-buckets variant measured 174µs vs ~80, reverted r11).
template<bool LAST>
__global__ __launch_bounds__(256) void mlp2_update_next_kernel(
    const u16* __restrict__ sbf_mid, const float* __restrict__ s_mid,
    const float* __restrict__ v_mid,
    const u16* __restrict__ Uv, const u16* __restrict__ Vv,
    const u16* __restrict__ W1, const float* __restrict__ b1,
    const u16* __restrict__ W2, const float* __restrict__ b2,
    float* __restrict__ s_out,
    float* __restrict__ v_out, u16* __restrict__ v_pk,
    const u16* __restrict__ N_W1, const float* __restrict__ N_b1,
    const u16* __restrict__ N_W2, const float* __restrict__ N_b2,
    u16* __restrict__ a_pk,
    const u16* __restrict__ H_W1, const float* __restrict__ H_b1,
    const float* __restrict__ ow2, const float* __restrict__ ob2,
    float* __restrict__ nodeval, int M)
{
    __shared__ u16 As[BM2][KB + LPAD];
    __shared__ u16 Ws[128][KB + LPAD];
    u16 (*T)[KB + LPAD] = &Ws[64];     // alias: valid only after GEMM1 consumed Ws
    const int bm = blockIdx.x * BM2;
    const int tid = threadIdx.x;
    const int wave = tid >> 6, lane = tid & 63;
    const int wrow = (wave >> 1) * 16;      // 0 or 16
    const int wn1  = (wave & 1) * 64;       // GEMM1 col-half
    const int wn   = (wave & 1) * 32;       // GEMM2 col-half
    const int quad = lane >> 4, lr = lane & 15;
    const int r = tid >> 2, q = tid & 3;    // Ws staging (128 rows)
    const int r3 = tid >> 3, c16 = (tid & 7) * 16;  // As staging (32 rows x 128 cols)

    floatx4 acc1[4];
    #pragma unroll
    for (int j = 0; j < 4; j++) acc1[j] = (floatx4)0.f;

    // ---- GEMM1, ko chunk 0: A cols = s_mid bf16
    {
        int gm = bm + r3;
        u16* dA = &As[r3][c16];
        if (gm < M) {
            const u16* ap = sbf_mid + (size_t)gm * FD + c16;
            *(bf16x8*)&dA[0] = *(const bf16x8*)(ap);
            *(bf16x8*)&dA[8] = *(const bf16x8*)(ap + 8);
        } else {
            *(bf16x8*)&dA[0] = (bf16x8)0;
            *(bf16x8*)&dA[8] = (bf16x8)0;
        }
        #pragma unroll
        for (int h = 0; h < 2; h++) {
            int wr = r + h * 64;
            const u16* wp = W1 + (size_t)wr * F2 + q * 32;
            u16* dW = &Ws[wr][q * 32];
            #pragma unroll
            for (int x = 0; x < 32; x += 8)
                *(bf16x8*)&dW[x] = *(const bf16x8*)(wp + x);
        }
    }
    __syncthreads();
    #pragma unroll
    for (int kk = 0; kk < KB; kk += 32) {
        bf16x8 a0 = *(const bf16x8*)&As[wrow + lr][kk + quad * 8];
        #pragma unroll
        for (int j = 0; j < 4; j++) {
            bf16x8 b = *(const bf16x8*)&Ws[wn1 + j * 16 + lr][kk + quad * 8];
            acc1[j] = __builtin_amdgcn_mfma_f32_16x16x32_bf16(a0, b, acc1[j], 0, 0, 0);
        }
    }
    __syncthreads();
    // ---- GEMM1, ko chunk 1: A cols = |Vv| computed inline (build_h fused)
    {
        int gm = bm + r3;
        u16* dA = &As[r3][c16];
        if (gm < M) {
            const u16* vvp = Vv + (size_t)gm * F3 + c16;
            #pragma unroll
            for (int t = 0; t < 2; t++) {
                bf16x8 c0 = *(const bf16x8*)(vvp + t * 8);
                bf16x8 c1 = *(const bf16x8*)(vvp + FD + t * 8);
                bf16x8 c2 = *(const bf16x8*)(vvp + 2 * FD + t * 8);
                #pragma unroll
                for (int x = 0; x < 8; x++) {
                    float a = b2f((u16)c0[x]);
                    float b = b2f((u16)c1[x]);
                    float c = b2f((u16)c2[x]);
                    dA[t * 8 + x] = f2b(sqrtf(a * a + b * b + c * c));
                }
            }
        } else {
            *(bf16x8*)&dA[0] = (bf16x8)0;
            *(bf16x8*)&dA[8] = (bf16x8)0;
        }
        #pragma unroll
        for (int h = 0; h < 2; h++) {
            int wr = r + h * 64;
            const u16* wp = W1 + (size_t)wr * F2 + KB + q * 32;
            u16* dW = &Ws[wr][q * 32];
            #pragma unroll
            for (int x = 0; x < 32; x += 8)
                *(bf16x8*)&dW[x] = *(const bf16x8*)(wp + x);
        }
    }
    __syncthreads();
    #pragma unroll
    for (int kk = 0; kk < KB; kk += 32) {
        bf16x8 a0 = *(const bf16x8*)&As[wrow + lr][kk + quad * 8];
        #pragma unroll
        for (int j = 0; j < 4; j++) {
            bf16x8 b = *(const bf16x8*)&Ws[wn1 + j * 16 + lr][kk + quad * 8];
            acc1[j] = __builtin_amdgcn_mfma_f32_16x16x32_bf16(a0, b, acc1[j], 0, 0, 0);
        }
    }
    __syncthreads();   // all MFMAs done reading Ws -> T region writable
    // T = silu(acc1 + b1) as bf16  (rows 0..31 of Ws[64..])
    #pragma unroll
    for (int j = 0; j < 4; j++) {
        int col = wn1 + j * 16 + lr;
        float bb = b1[col];
        #pragma unroll
        for (int rr = 0; rr < 4; rr++) {
            int row = wrow + quad * 4 + rr;
            float v = acc1[j][rr] + bb;
            v = v / (1.f + __expf(-v));
            T[row][col] = f2b(v);
        }
    }

    // ---- GEMM2: pieces staged into Ws[0..63]; order (avv,asv,ass) per f-half.
    float avvr[2][4], asvr[2][4];
    #pragma unroll
    for (int pp = 0; pp < 6; pp++) {
        const int part  = pp / 3;
        const int piece = pp % 3;
        const int c0 = piece * 128 + part * 64;
        {
            const u16* wp = W2 + (size_t)(c0 + r) * KB + q * 32;
            u16* dW = &Ws[r][q * 32];
            #pragma unroll
            for (int x = 0; x < 32; x += 8)
                *(bf16x8*)&dW[x] = *(const bf16x8*)(wp + x);
        }
        __syncthreads();   // (pp==0: also covers T-write)
        floatx4 acc2[2];
        #pragma unroll
        for (int j = 0; j < 2; j++) acc2[j] = (floatx4)0.f;
        #pragma unroll
        for (int kk = 0; kk < KB; kk += 32) {
            bf16x8 a0 = *(const bf16x8*)&T[wrow + lr][kk + quad * 8];
            bf16x8 b0 = *(const bf16x8*)&Ws[wn + lr     ][kk + quad * 8];
            bf16x8 b1 = *(const bf16x8*)&Ws[wn + 16 + lr][kk + quad * 8];
            acc2[0] = __builtin_amdgcn_mfma_f32_16x16x32_bf16(a0, b0, acc2[0], 0, 0, 0);
            acc2[1] = __builtin_amdgcn_mfma_f32_16x16x32_bf16(a0, b1, acc2[1], 0, 0, 0);
        }
        if (piece == 0) {
            #pragma unroll
            for (int j = 0; j < 2; j++) {
                int gn = c0 + wn + j * 16 + lr;
                float bb = b2[gn];
                #pragma unroll
                for (int rr = 0; rr < 4; rr++)
                    avvr[j][rr] = acc2[j][rr] + bb;
            }
        } else if (piece == 1) {
            #pragma unroll
            for (int j = 0; j < 2; j++) {
                int gn = c0 + wn + j * 16 + lr;
                float bb = b2[gn];
                #pragma unroll
                for (int rr = 0; rr < 4; rr++)
                    asvr[j][rr] = acc2[j][rr] + bb;
            }
        } else {
            // ass chunk: full node update + As s-deposit
            #pragma unroll
            for (int j = 0; j < 2; j++) {
                int gn = c0 + wn + j * 16 + lr;
                int f  = gn - 256;          // = part*64 + wn + j*16 + lr
                float bb = b2[gn];
                #pragma unroll
                for (int rr = 0; rr < 4; rr++) {
                    int row = wrow + quad * 4 + rr;
                    int gm = bm + row;
                    if (gm < M) {
                        float ass = acc2[j][rr] + bb;
                        float asv = asvr[j][rr];
                        float avv = avvr[j][rr];
                        int vb = gm * F3 + f;
                        float u0 = b2f(Uv[vb]);
                        float u1 = b2f(Uv[vb + FD]);
                        float u2 = b2f(Uv[vb + 2 * FD]);
                        float w0 = b2f(Vv[vb]);
                        float w1 = b2f(Vv[vb + FD]);
                        float w2 = b2f(Vv[vb + 2 * FD]);
                        float dot = u0 * w0 + u1 * w1 + u2 * w2;
                        int nb = gm * FD + f;
                        float so = s_mid[nb] + ass + asv * dot;
                        s_out[nb] = so;
                        As[row][f] = f2b(so);
                        float y0 = v_mid[vb]          + avv * u0;
                        float y1 = v_mid[vb + FD]     + avv * u1;
                        float y2 = v_mid[vb + 2 * FD] + avv * u2;
                        v_out[vb]          = y0;
                        v_out[vb + FD]     = y1;
                        v_out[vb + 2 * FD] = y2;
                        char* vpb = (char*)v_pk + (size_t)gm * (2 * F3);
                        *(u32*)(vpb + 4 * f) = pack2(y0, y1);
                        *(u16*)(vpb + 512 + 2 * f) = f2b(y2);
                    } else {
                        As[row][f] = 0;
                    }
                }
            }
        }
        __syncthreads();   // piece consumed (and As deposit visible) before restage
    }
    // As now holds this block's fresh s (bf16), 32 rows x 128 cols.

    if constexpr (!LAST) {
        // ---------------- appended mlp1 of next iteration (A = As, K=128)
        {
            #pragma unroll
            for (int h = 0; h < 2; h++) {
                int wr = r + h * 64;
                const u16* wp = N_W1 + (size_t)wr * KB + q * 32;
                u16* dW = &Ws[wr][q * 32];
                #pragma unroll
                for (int x = 0; x < 32; x += 8)
                    *(bf16x8*)&dW[x] = *(const bf16x8*)(wp + x);
            }
        }
        __syncthreads();
        #pragma unroll
        for (int j = 0; j < 4; j++) acc1[j] = (floatx4)0.f;
        #pragma unroll
        for (int kk = 0; kk < KB; kk += 32) {
            bf16x8 a0 = *(const bf16x8*)&As[wrow + lr][kk + quad * 8];
            #pragma unroll
            for (int j = 0; j < 4; j++) {
                bf16x8 b = *(const bf16x8*)&Ws[wn1 + j * 16 + lr][kk + quad * 8];
                acc1[j] = __builtin_amdgcn_mfma_f32_16x16x32_bf16(a0, b, acc1[j], 0, 0, 0);
            }
        }
        __syncthreads();   // Ws consumed -> T region writable
        #pragma unroll
        for (int j = 0; j < 4; j++) {
            int col = wn1 + j * 16 + lr;
            float bb = N_b1[col];
            #pragma unroll
            for (int rr = 0; rr < 4; rr++) {
                int row = wrow + quad * 4 + rr;
                float v = acc1[j][rr] + bb;
                v = v / (1.f + __expf(-v));
                T[row][col] = f2b(v);
            }
        }
        // GEMM2 (6 pieces of 64 cols into Ws[0..63])
        for (int pp = 0; pp < 6; pp++) {
            const int c0 = pp * 64;
            {
                const u16* wp = N_W2 + (size_t)(c0 + r) * KB + q * 32;
                u16* dW = &Ws[r][q * 32];
                #pragma unroll
                for (int x = 0; x < 32; x += 8)
                    *(bf16x8*)&dW[x] = *(const bf16x8*)(wp + x);
            }
            __syncthreads();   // (pp==0: also covers T-write)
            floatx4 acc2[2];
            #pragma unroll
            for (int j = 0; j < 2; j++) acc2[j] = (floatx4)0.f;
            #pragma unroll
            for (int kk = 0; kk < KB; kk += 32) {
                bf16x8 a0 = *(const bf16x8*)&T[wrow + lr][kk + quad * 8];
                bf16x8 b0 = *(const bf16x8*)&Ws[wn + lr     ][kk + quad * 8];
                bf16x8 b1 = *(const bf16x8*)&Ws[wn + 16 + lr][kk + quad * 8];
                acc2[0] = __builtin_amdgcn_mfma_f32_16x16x32_bf16(a0, b0, acc2[0], 0, 0, 0);
                acc2[1] = __builtin_amdgcn_mfma_f32_16x16x32_bf16(a0, b1, acc2[1], 0, 0, 0);
            }
            #pragma unroll
            for (int j = 0; j < 2; j++) {
                int gn = c0 + wn + j * 16 + lr;
                float bb = N_b2[gn];
                #pragma unroll
                for (int rr = 0; rr < 4; rr++) {
                    int gm = bm + wrow + quad * 4 + rr;
                    if (gm < M) {
                        u16 val = f2b(acc2[j][rr] + bb);
                        int off = (gn < 256) ? ((gn & 127) * 2 + (gn >> 7))
                                             : (256 + (gn & 127));
                        a_pk[(size_t)gm * F3 + off] = val;
                    }
                }
            }
            __syncthreads();
        }
    } else {
        // ---------------- appended final head: t = silu(s@ow1^T+ob1); nodeval = t·ow2 + ob2
        {
            #pragma unroll
            for (int h = 0; h < 2; h++) {
                int wr = r + h * 64;
                const u16* wp = H_W1 + (size_t)wr * KB + q * 32;
                u16* dW = &Ws[wr][q * 32];
                #pragma unroll
                for (int x = 0; x < 32; x += 8)
                    *(bf16x8*)&dW[x] = *(const bf16x8*)(wp + x);
            }
        }
        __syncthreads();
        #pragma unroll
        for (int j = 0; j < 4; j++) acc1[j] = (floatx4)0.f;
        #pragma unroll
        for (int kk = 0; kk < KB; kk += 32) {
            bf16x8 a0 = *(const bf16x8*)&As[wrow + lr][kk + quad * 8];
            #pragma unroll
            for (int j = 0; j < 4; j++) {
                bf16x8 b = *(const bf16x8*)&Ws[wn1 + j * 16 + lr][kk + quad * 8];
                acc1[j] = __builtin_amdgcn_mfma_f32_16x16x32_bf16(a0, b, acc1[j], 0, 0, 0);
            }
        }
        __syncthreads();   // Ws + As fully consumed
        float* ow2s = (float*)&As[0][0];   // 128 f32 (As dead)
        if (tid < KB) ow2s[tid] = ow2[tid];
        #pragma unroll
        for (int j = 0; j < 4; j++) {
            int col = wn1 + j * 16 + lr;
            float bb = H_b1[col];
            #pragma unroll
            for (int rr = 0; rr < 4; rr++) {
                int row = wrow + quad * 4 + rr;
                float v = acc1[j][rr] + bb;
                v = v / (1.f + __expf(-v));
                T[row][col] = f2b(v);      // bf16 t in Ws[64..]
            }
        }
        __syncthreads();
        // dot with ow2: 8 threads per node, 16 cols each, shfl-reduce within 8-lane group
        int nl = tid >> 3, seg = tid & 7;
        float v = 0.f;
        #pragma unroll
        for (int x = 0; x < 16; x++) {
            int col = seg * 16 + x;
            v += b2f(T[nl][col]) * ow2s[col];
        }
        v += __shfl_down(v, 4);
        v += __shfl_down(v, 2);
        v += __shfl_down(v, 1);
        if (seg == 0) {
            int gm = bm + nl;
            if (gm < M) nodeval[gm] = v + ob2[0];
        }
    }
}

// Multi-block molecule reduce: per-block LDS buckets (pre-reduce), then 64 global atomics.
// out zeroed in init_all each launch (replay-safe).
__global__ __launch_bounds__(256) void mol_reduce_kernel(const float* __restrict__ nodeval,
    const int* __restrict__ gidx, float* __restrict__ out)
{
    __shared__ float mol[NMOL];
    int tid = threadIdx.x;
    if (tid < NMOL) mol[tid] = 0.f;
    __syncthreads();
    int x = blockIdx.x * 256 + tid;
    if (x < NN) atomicAdd(&mol[gidx[x]], nodeval[x]);
    __syncthreads();
    if (tid < NMOL && mol[tid] != 0.f) atomicAdd(&out[tid], mol[tid]);
}

// ---------------------------------------------------------------- launch
extern "C" void kernel_launch(void* const* d_in, const int* in_sizes, int n_in,
                              void* d_out, int out_size, void* d_ws, size_t ws_size,
                              hipStream_t stream)
{
    const int*   z     = (const int*)d_in[0];
    const int*   graph = (const int*)d_in[1];
    const float* dist  = (const float*)d_in[2];
    const float* sense = (const float*)d_in[3];
    const int*   gidx  = (const int*)d_in[4];
    const float* emb   = (const float*)d_in[5];
    const float* mw1   = (const float*)d_in[6];
    const float* mb1   = (const float*)d_in[7];
    const float* mw2   = (const float*)d_in[8];
    const float* mb2   = (const float*)d_in[9];
    const float* ew    = (const float*)d_in[10];
    const float* eb    = (const float*)d_in[11];
    const float* uw    = (const float*)d_in[12];
    const float* vw    = (const float*)d_in[13];
    const float* aw1   = (const float*)d_in[14];
    const float* ab1   = (const float*)d_in[15];
    const float* aw2   = (const float*)d_in[16];
    const float* ab2   = (const float*)d_in[17];
    const float* ow1   = (const float*)d_in[18];
    const float* ob1   = (const float*)d_in[19];
    const float* ow2   = (const float*)d_in[20];
    const float* ob2   = (const float*)d_in[21];
    float* out = (float*)d_out;

    // ---- workspace carve-up ----
    float* W = (float*)d_ws;
    float* s_a    = W; W += (size_t)NN * FD;
    float* s_b    = W; W += (size_t)NN * FD;
    float* v_a    = W; W += (size_t)NN * F3;
    float* v_b    = W; W += (size_t)NN * F3;
    float* cut_p  = W; W += (size_t)NE;
    float* sns_p  = W; W += (size_t)NE * 3;
    float* nodeval= W; W += (size_t)NN;
    u16* U = (u16*)W;
    u16* sbf_a = U; U += (size_t)NN * FD;
    u16* sbf_b = U; U += (size_t)NN * FD;
    u16* vbf_b = U; U += (size_t)NN * F3;
    u16* a_pk  = U; U += (size_t)NN * F3;
    u16* v_pk  = U; U += (size_t)NN * F3;
    u16* h_bf  = U; U += (size_t)NN * F2;   // unused (layout stability)
    u16* a2_bf = U; U += (size_t)NN * F3;   // unused (layout stability)
    u16* Uv_bf = U; U += (size_t)NN * F3;
    u16* Vv_bf = U; U += (size_t)NN * F3;
    u16* rbf_bf= U; U += (size_t)NE * 32;
    u16* ewb   = U; U += (size_t)NITER * F3 * 32;
    u16* wb    = U; U += 557056;
    int* ip = (int*)U;
    int* row_ptr   = ip; ip += NN + 1;
    int* cnt       = ip; ip += NN;
    int* cursor    = ip; ip += NN;
    int* edge_list = ip; ip += NE;
    int* dst_p     = ip; ip += NE;

    // bf16 weight table offsets
    u16* wb_mw1 = wb;            // 3*128*128
    u16* wb_mw2 = wb + 49152;    // 3*384*128
    u16* wb_uw  = wb + 196608;   // 3*128*128
    u16* wb_vw  = wb + 245760;   // 3*128*128
    u16* wb_aw1 = wb + 294912;   // 3*128*256
    u16* wb_aw2 = wb + 393216;   // 3*384*128
    u16* wb_ow1 = wb + 540672;   // 128*128

    const int TB = 256;
    dim3 b256(TB);

    // --- precompute ---
    init_all_kernel<<<dim3((NN * F3 + TB - 1) / TB), b256, 0, stream>>>(
        mw1, 49152, mw2, 147456, uw, 49152, vw, 49152, aw1, 98304, aw2, 147456,
        ow1, 16384, wb, ew, ewb, z, emb, s_a, sbf_a, v_a, (int*)v_pk, cnt, out);
    csr_count_kernel<<<dim3((NE + TB - 1) / TB), b256, 0, stream>>>(graph, cnt);
    csr_scan_kernel<<<dim3(1), dim3(1024), 0, stream>>>(cnt, row_ptr, cursor);
    csr_scatter_kernel<<<dim3((NE + TB - 1) / TB), b256, 0, stream>>>(graph, cursor, edge_list);
    edge_stream_kernel<<<dim3((NE + TB - 1) / TB), b256, 0, stream>>>(
        edge_list, graph, dist, sense, rbf_bf, cut_p, sns_p, dst_p);

    dim3 gM2((NN + BM2 - 1) / BM2);             // node kernels (BM=32, 625 blocks)
    dim3 gUV((3 * NN + BM2 - 1) / BM2);         // gemm_uv (BM=32, 1875 blocks)
    dim3 gE(NN, 2);                             // edge kernel: f-split, 2 blocks/node

    // iter-0 message MLP (later iterations' mlp1 are fused into mlp2_update_next)
    mlp1_kernel<<<gM2, b256, 0, stream>>>(sbf_a,
        wb_mw1, mb1, wb_mw2, mb2, a_pk, NN);

    for (int i = 0; i < NITER; i++) {
        edge_mfma_kernel<<<gE, dim3(128), 0, stream>>>(
            rbf_bf, cut_p, sns_p, dst_p,
            ewb + (size_t)i * F3 * 32, eb + (size_t)i * F3,
            a_pk, s_a, v_a, v_pk, row_ptr, s_b, sbf_b, v_b, vbf_b);
        gemm_uv<<<gUV, b256, 0, stream>>>(vbf_b, wb_uw + (size_t)i * FD * FD,
            wb_vw + (size_t)i * FD * FD, Uv_bf, Vv_bf, 3 * NN);
        if (i < NITER - 1) {
            mlp2_update_next_kernel<false><<<gM2, b256, 0, stream>>>(
                sbf_b, s_b, v_b, Uv_bf, Vv_bf,
                wb_aw1 + (size_t)i * FD * F2, ab1 + (size_t)i * FD,
                wb_aw2 + (size_t)i * F3 * FD, ab2 + (size_t)i * F3,
                s_a, v_a, v_pk,
                wb_mw1 + (size_t)(i + 1) * FD * FD, mb1 + (size_t)(i + 1) * FD,
                wb_mw2 + (size_t)(i + 1) * F3 * FD, mb2 + (size_t)(i + 1) * F3, a_pk,
                nullptr, nullptr, nullptr, nullptr, nullptr, NN);
        } else {
            mlp2_update_next_kernel<true><<<gM2, b256, 0, stream>>>(
                sbf_b, s_b, v_b, Uv_bf, Vv_bf,
                wb_aw1 + (size_t)i * FD * F2, ab1 + (size_t)i * FD,
                wb_aw2 + (size_t)i * F3 * FD, ab2 + (size_t)i * F3,
                s_a, v_a, v_pk,
                nullptr, nullptr, nullptr, nullptr, nullptr,
                wb_ow1, ob1, ow2, ob2, nodeval, NN);
        }
    }

    mol_reduce_kernel<<<dim3((NN + TB - 1) / TB), b256, 0, stream>>>(nodeval, gidx, out);
}